// Round 5
// baseline (513.803 us; speedup 1.0000x reference)
//
#include <hip/hip_runtime.h>
#include <hip/hip_bf16.h>
#include <math.h>

#define HIDDEN 2048
#define NH 16
#define HD 128
#define NB 2
#define SEQ 2048
#define K_DIM 2048

typedef unsigned int u32;
typedef unsigned short ushort_t;
typedef __bf16 bf16x8 __attribute__((ext_vector_type(8)));
typedef float f32x4 __attribute__((ext_vector_type(4)));
typedef ushort_t u16x8 __attribute__((ext_vector_type(8)));

// ---------- fp32 -> (bf16 hi, bf16 lo) split, RNE both halves ----------
__device__ __forceinline__ void split1(float x, unsigned short& h, unsigned short& l) {
    u32 u = __float_as_uint(x);
    u32 hr = (u + 0x7FFFu + ((u >> 16) & 1u)) >> 16;
    h = (unsigned short)hr;
    float r = x - __uint_as_float(hr << 16);
    u32 u2 = __float_as_uint(r);
    l = (unsigned short)((u2 + 0x7FFFu + ((u2 >> 16) & 1u)) >> 16);
}

__device__ __forceinline__ ushort_t bf16r(float x) {
    u32 u = __float_as_uint(x);
    return (ushort_t)((u + 0x7FFFu + ((u >> 16) & 1u)) >> 16);
}

__device__ __forceinline__ void gl_lds16(const void* g, void* l) {
    __builtin_amdgcn_global_load_lds(
        (const __attribute__((address_space(1))) u32*)g,
        (__attribute__((address_space(3))) u32*)l, 16, 0, 0);
}

// ==================== RoPE tables (double-precision trig) ====================
__global__ void k_rope_tables(float* __restrict__ ct, float* __restrict__ st) {
    int idx = blockIdx.x * 256 + threadIdx.x;   // exactly SEQ*64 threads
    int s = idx >> 6, d = idx & 63;
    double inv = pow(10000.0, -(double)d * (1.0 / 64.0));
    double ang = (double)s * inv;
    ct[idx] = (float)cos(ang);
    st[idx] = (float)sin(ang);
}

// ==================== fused fp32 -> bf16 (hi only) for X, Wq, Wk, Wv ========
#define XG 2097152   // X float4 groups
#define WG 1048576   // W float4 groups
__global__ void k_cvt_all(const float4* __restrict__ X, const float4* __restrict__ W0,
                          const float4* __restrict__ W1, const float4* __restrict__ W2,
                          ushort4* __restrict__ Xh, ushort4* __restrict__ H0,
                          ushort4* __restrict__ H1, ushort4* __restrict__ H2) {
    int idx = blockIdx.x * 256 + threadIdx.x;   // XG + 3*WG threads
    const float4* src;
    ushort4* dst;
    int off;
    if (idx < XG) { src = X; dst = Xh; off = idx; }
    else {
        int t = idx - XG;
        int m = t >> 20;        // WG = 2^20
        off = t & (WG - 1);
        src = (m == 0) ? W0 : (m == 1) ? W1 : W2;
        dst = (m == 0) ? H0 : (m == 1) ? H1 : H2;
    }
    float4 x = src[off];
    ushort4 h;
    h.x = bf16r(x.x); h.y = bf16r(x.y); h.z = bf16r(x.z); h.w = bf16r(x.w);
    dst[off] = h;
}

// ==================== fp32 -> bf16 hi/lo split (Wo only) =====================
__global__ void k_split(const float4* __restrict__ src, ushort4* __restrict__ hi,
                        ushort4* __restrict__ lo) {
    int idx = blockIdx.x * 256 + threadIdx.x;
    float4 x = src[idx];
    ushort4 h, l;
    split1(x.x, h.x, l.x);
    split1(x.y, h.y, l.y);
    split1(x.z, h.z, l.z);
    split1(x.w, h.w, l.w);
    hi[idx] = h;
    lo[idx] = l;
}

// ==================== common waitcnt/barrier macros ==========================
#define BAR  __builtin_amdgcn_s_barrier()
#define VM6  asm volatile("s_waitcnt vmcnt(6)" ::: "memory")
#define VM4  asm volatile("s_waitcnt vmcnt(4)" ::: "memory")
#define VM0  asm volatile("s_waitcnt vmcnt(0)" ::: "memory")
#define PRIO1 __builtin_amdgcn_s_setprio(1)
#define PRIO0 __builtin_amdgcn_s_setprio(0)

// ==================== fused QKV: 256x256, BK=32, 4-slot rotation =============
// R5: gates restored to the PROVEN pre-barrier form (R1/R2 passed with it).
// Phase p = {STAGE(tile p+2 -> slot (p+2)&3); VM4; BAR_p; RD(tile p+1 ->
// other reg set); MFMA(tile p on current set)}.
// Invariant A (gate): VM4 pre-BAR -> at BAR_p every wave certified its
// tile-(p+1) loads complete (4 newest outstanding = tile p+2) -> cross-wave
// reads post-BAR_p are safe.
// Invariant B (anti-overwrite): stage@p targets slot (p+2)&3 = slot of tile
// p-2; tile p-2's reads (issued @p-3) were lgkm-drained by their consuming
// MFMA in region [BAR_{p-2}, BAR_{p-1}]; the overwriting DMA issues
// post-BAR_{p-1} (program order) -> one full barrier between drain and
// overwrite. S=4 slots >= L+2 with L=2.
// Counted vmcnt: 4-8 loads in flight at all times, never 0 mid-loop.
// Swizzle: LDS[r][slot c] holds global 16B-slot c^((r>>1)&3); rows stride
// 64B so (r>>1) XOR gives exactly 2 lanes/bank (free per m136).
#define QSTAGE(slot, kt) do { \
    const ushort_t* gA_ = Xh + sgA + (size_t)(kt) * 32; \
    gl_lds16(gA_, &As[slot][(w * 32) * 32]); \
    gl_lds16(gA_ + 16 * 2048, &As[slot][(w * 32 + 16) * 32]); \
    const ushort_t* gB_ = Wsel + sgB + (size_t)(kt) * 32; \
    gl_lds16(gB_, &Bs[slot][(w * 32) * 32]); \
    gl_lds16(gB_ + 16 * 2048, &Bs[slot][(w * 32 + 16) * 32]); \
} while (0)

#define QRD(AD, BD, slot) do { \
    _Pragma("unroll") for (int mf = 0; mf < 8; mf++) \
        AD[mf] = *(const bf16x8*)&As[slot][arow + mf * 512 + ccq]; \
    _Pragma("unroll") for (int nf = 0; nf < 4; nf++) \
        BD[nf] = *(const bf16x8*)&Bs[slot][brow + nf * 512 + ccq]; \
} while (0)

#define QMFMA(AD, BD) do { PRIO1; \
    _Pragma("unroll") for (int mf = 0; mf < 8; mf++) \
    _Pragma("unroll") for (int nf = 0; nf < 4; nf++) \
        acc[mf][nf] = __builtin_amdgcn_mfma_f32_16x16x32_bf16( \
            AD[mf], BD[nf], acc[mf][nf], 0, 0, 0); \
    PRIO0; } while (0)

__global__ __launch_bounds__(512, 2)
void k_gemm_qkv8(const ushort_t* __restrict__ Xh,
                 const ushort_t* __restrict__ W0, const ushort_t* __restrict__ W1,
                 const ushort_t* __restrict__ W2,
                 const float* __restrict__ b0, const float* __restrict__ b1,
                 const float* __restrict__ b2,
                 float* __restrict__ o0, float* __restrict__ o1, float* __restrict__ o2) {
    __shared__ ushort_t As[4][256 * 32];
    __shared__ ushort_t Bs[4][256 * 32];
    const int tid = threadIdx.x;
    const int lane = tid & 63;
    const int w = tid >> 6;        // wave 0..7
    const int wm = w >> 2;         // 0..1  (128 output rows each)
    const int wn = w & 3;          // 0..3  (64 output cols each)
    const int quad = lane >> 4;
    const int l15 = lane & 15;

    // bijective XCD swizzle (384 % 8 == 0)
    int bid = blockIdx.x;
    bid = (bid & 7) * 48 + (bid >> 3);
    const int bx = bid & 15;       // m-block
    const int by = bid >> 4;       // 0..23
    const int m0 = bx << 8;
    const int mat = by >> 3;
    const int n0 = (by & 7) << 8;
    const ushort_t* Wsel = (mat == 0) ? W0 : (mat == 1) ? W1 : W2;
    const float* bias = (mat == 0) ? b0 : (mat == 1) ? b1 : b2;
    float* out = (mat == 0) ? o0 : (mat == 1) ? o1 : o2;

    // staging: wave w covers rows [w*32, w*32+32); lane -> (row lrow4, slot
    // lane&3); global col slot pre-swizzled.
    const int lrow4 = lane >> 2;
    const int col8 = (((lane & 3) ^ ((lrow4 >> 1) & 3)) << 3);
    const size_t sgA = (size_t)(m0 + w * 32 + lrow4) * 2048 + col8;
    const size_t sgB = (size_t)(n0 + w * 32 + lrow4) * 2048 + col8;

    // fragment reads: row R wants global slot q -> LDS slot q^((R>>1)&3);
    // (R>>1)&3 == (l15>>1)&3 for R = base16 + l15
    const int arow = (wm * 128 + l15) * 32;
    const int brow = (wn * 64 + l15) * 32;
    const int ccq = ((quad ^ ((l15 >> 1) & 3)) << 3);

    f32x4 acc[8][4];
#pragma unroll
    for (int i = 0; i < 8; i++)
#pragma unroll
        for (int j = 0; j < 4; j++) acc[i][j] = (f32x4){0.f, 0.f, 0.f, 0.f};

    bf16x8 aA[8], bA[4], aB[8], bB[4];

    // prologue: tiles 0,1 staged; VM4 pre-BAR certifies tile0 for all waves
    QSTAGE(0, 0); QSTAGE(1, 1);
    VM4; BAR;
    QRD(aA, bA, 0);

    // phases 0..59 (15 iters x 4 phases; slots compile-time constants)
    for (int p = 0; p < 60; p += 4) {
        QSTAGE(2, p + 2); VM4; BAR; QRD(aB, bB, 1); QMFMA(aA, bA);   // tile p
        QSTAGE(3, p + 3); VM4; BAR; QRD(aA, bA, 2); QMFMA(aB, bB);   // tile p+1
        QSTAGE(0, p + 4); VM4; BAR; QRD(aB, bB, 3); QMFMA(aA, bA);   // tile p+2
        QSTAGE(1, p + 5); VM4; BAR; QRD(aA, bA, 0); QMFMA(aB, bB);   // tile p+3
    }
    // tail phases 60..63
    QSTAGE(2, 62); VM4; BAR; QRD(aB, bB, 1); QMFMA(aA, bA);          // tile 60
    QSTAGE(3, 63); VM4; BAR; QRD(aA, bA, 2); QMFMA(aB, bB);          // tile 61
    VM0; BAR;                QRD(aB, bB, 3); QMFMA(aA, bA);          // tile 62
    QMFMA(aB, bB);                                                   // tile 63

    // ---- epilogue: bias + store to blocked (B,NH,S,HD) fp32 ----
    float bcolv[4];
#pragma unroll
    for (int nf = 0; nf < 4; nf++) bcolv[nf] = bias[n0 + wn * 64 + nf * 16 + l15];

    const int mbase = m0 + wm * 128 + quad * 4;
#pragma unroll
    for (int mf = 0; mf < 8; mf++)
#pragma unroll
        for (int nf = 0; nf < 4; nf++) {
            const int n = n0 + wn * 64 + nf * 16 + l15;
            const int hh = n >> 7;
            const int d = n & 127;
#pragma unroll
            for (int r = 0; r < 4; r++) {
                const int m = mbase + mf * 16 + r;
                const int bb = m >> 11;
                const int s = m & (SEQ - 1);
                out[((size_t)(bb * NH + hh) * SEQ + s) * HD + d] = acc[mf][nf][r] + bcolv[nf];
            }
        }
}

// ==================== O-projection: 256x128, BK=32, 3-slot rotation ==========
// S=3 is the LDS max (144 KiB), so stage distance L=2 forces the stage
// POST-barrier and the gate becomes VM0 PRE-barrier:
// phase q = {VM0; BAR_q; STAGE(tile q+2 -> slot (q+2)%3);
//            RD(tile q+1 <- slot (q+1)%3); MFMA(tile q)}.
// Invariant A: tile q+1 was staged @ q-1 post-BAR_{q-1}; VM0@q pre-BAR
// drains it per-wave -> certified globally at BAR_q. Drain cost ~0: the
// loads are ~1 full MFMA phase (~1900cy) old > HBM latency.
// Invariant B: slot (q+2)%3 holds tile q-1, whose reads (issued @q-2) were
// lgkm-drained by MFMA@q-1 in region [BAR_{q-1}, BAR_q]; overwrite DMA
// issues post-BAR_q -> barrier separates.
// bf16x3 hi/lo GEMM: 48 MFMA vs 16 ds_read per wave-phase -> MFMA-bound.
// Grid 16x16 = 256 blocks = perfect 1-generation packing.
// A (ctx hi/lo) is BLOCKED (B,NH,S,HD): tile kt -> (kt>>2)*SEQ*HD + (kt&3)*32.
#define OSTAGE(slot, kt) do { \
    const size_t koA = (size_t)((kt) >> 2) * ((size_t)SEQ * HD) + (size_t)((kt) & 3) * 32; \
    const size_t koB = (size_t)(kt) * 32; \
    gl_lds16(Ah + sgA0 + koA, &Ah_s[slot][(w * 32) * 32]); \
    gl_lds16(Ah + sgA0 + 16 * HD + koA, &Ah_s[slot][(w * 32 + 16) * 32]); \
    gl_lds16(Al + sgA0 + koA, &Al_s[slot][(w * 32) * 32]); \
    gl_lds16(Al + sgA0 + 16 * HD + koA, &Al_s[slot][(w * 32 + 16) * 32]); \
    gl_lds16(Bh + sgB0 + koB, &Bh_s[slot][(w * 16) * 32]); \
    gl_lds16(Bl + sgB0 + koB, &Bl_s[slot][(w * 16) * 32]); \
} while (0)

#define ORD(AH, AL, BH, BL, slot) do { \
    _Pragma("unroll") for (int f = 0; f < 4; f++) { \
        AH[f] = *(const bf16x8*)&Ah_s[slot][aro + f * 512 + cco]; \
        AL[f] = *(const bf16x8*)&Al_s[slot][aro + f * 512 + cco]; \
        BH[f] = *(const bf16x8*)&Bh_s[slot][bro + f * 512 + cco]; \
        BL[f] = *(const bf16x8*)&Bl_s[slot][bro + f * 512 + cco]; \
    } \
} while (0)

#define OMFMA(AH, AL, BH, BL) do { PRIO1; \
    _Pragma("unroll") for (int mf = 0; mf < 4; mf++) \
    _Pragma("unroll") for (int nf = 0; nf < 4; nf++) { \
        acc[mf][nf] = __builtin_amdgcn_mfma_f32_16x16x32_bf16( \
            AH[mf], BH[nf], acc[mf][nf], 0, 0, 0); \
        acc[mf][nf] = __builtin_amdgcn_mfma_f32_16x16x32_bf16( \
            AH[mf], BL[nf], acc[mf][nf], 0, 0, 0); \
        acc[mf][nf] = __builtin_amdgcn_mfma_f32_16x16x32_bf16( \
            AL[mf], BH[nf], acc[mf][nf], 0, 0, 0); \
    } PRIO0; } while (0)

__global__ __launch_bounds__(512, 2)
void k_gemm_o2(const ushort_t* __restrict__ Ah, const ushort_t* __restrict__ Al,
               const ushort_t* __restrict__ Bh, const ushort_t* __restrict__ Bl,
               const float* __restrict__ bias, float* __restrict__ out) {
    __shared__ ushort_t Ah_s[3][256 * 32];
    __shared__ ushort_t Al_s[3][256 * 32];
    __shared__ ushort_t Bh_s[3][128 * 32];
    __shared__ ushort_t Bl_s[3][128 * 32];
    const int tid = threadIdx.x;
    const int lane = tid & 63;
    const int w = tid >> 6;        // wave 0..7
    const int wm = w >> 1;         // 0..3 (64 output rows each)
    const int wn = w & 1;          // 0..1 (64 output cols each)
    const int quad = lane >> 4;
    const int l15 = lane & 15;

    // bijective XCD swizzle (256 % 8 == 0)
    int bid = blockIdx.x;
    bid = (bid & 7) * 32 + (bid >> 3);
    const int bx = bid & 15;       // m-block (0..15)
    const int by = bid >> 4;       // n-block (0..15)
    const int m0 = bx << 8;        // 256 rows
    const int n0 = by << 7;        // 128 cols

    // staging addressing (pre-swizzled global col slot, (r>>1)&3 XOR)
    const int lrow4 = lane >> 2;
    const int col8 = (((lane & 3) ^ ((lrow4 >> 1) & 3)) << 3);
    const size_t sgA0 = ((size_t)(m0 >> 11) * NH * SEQ + (size_t)((m0 & (SEQ - 1)) + w * 32 + lrow4)) * HD + col8;
    const size_t sgB0 = (size_t)(n0 + w * 16 + lrow4) * K_DIM + col8;

    // fragment reads
    const int aro = (wm * 64 + l15) * 32;
    const int bro = (wn * 64 + l15) * 32;
    const int cco = ((quad ^ ((l15 >> 1) & 3)) << 3);

    f32x4 acc[4][4];
#pragma unroll
    for (int i = 0; i < 4; i++)
#pragma unroll
        for (int j = 0; j < 4; j++) acc[i][j] = (f32x4){0.f, 0.f, 0.f, 0.f};

    bf16x8 ahA[4], alA[4], bhA[4], blA[4];
    bf16x8 ahB[4], alB[4], bhB[4], blB[4];

    // prologue: tiles 0,1 staged; VM6 pre-BAR certifies tile0 for all waves
    OSTAGE(0, 0);
    OSTAGE(1, 1);
    VM6; BAR;
    ORD(ahA, alA, bhA, blA, 0);

    // phases 0..59 (10 iters x 6 phases; slot/set pattern period 6)
    for (int it = 0; it < 10; ++it) {
        const int q = 6 * it;
        VM0; BAR; OSTAGE(2, q + 2); ORD(ahB, alB, bhB, blB, 1); OMFMA(ahA, alA, bhA, blA);  // tile q
        VM0; BAR; OSTAGE(0, q + 3); ORD(ahA, alA, bhA, blA, 2); OMFMA(ahB, alB, bhB, blB);  // q+1
        VM0; BAR; OSTAGE(1, q + 4); ORD(ahB, alB, bhB, blB, 0); OMFMA(ahA, alA, bhA, blA);  // q+2
        VM0; BAR; OSTAGE(2, q + 5); ORD(ahA, alA, bhA, blA, 1); OMFMA(ahB, alB, bhB, blB);  // q+3
        VM0; BAR; OSTAGE(0, q + 6); ORD(ahB, alB, bhB, blB, 2); OMFMA(ahA, alA, bhA, blA);  // q+4
        VM0; BAR; OSTAGE(1, q + 7); ORD(ahA, alA, bhA, blA, 0); OMFMA(ahB, alB, bhB, blB);  // q+5
    }
    // tail phases 60..63
    VM0; BAR; OSTAGE(2, 62); ORD(ahB, alB, bhB, blB, 1); OMFMA(ahA, alA, bhA, blA);  // tile 60
    VM0; BAR; OSTAGE(0, 63); ORD(ahA, alA, bhA, blA, 2); OMFMA(ahB, alB, bhB, blB);  // tile 61
    VM0; BAR;                ORD(ahB, alB, bhB, blB, 0); OMFMA(ahA, alA, bhA, blA);  // tile 62
    OMFMA(ahB, alB, bhB, blB);                                                        // tile 63

    // ---- epilogue: bias + coalesced fp32 store ----
    float bcolv[4];
#pragma unroll
    for (int nf = 0; nf < 4; nf++) bcolv[nf] = bias[n0 + wn * 64 + nf * 16 + l15];

    const int mb = m0 + wm * 64 + quad * 4;
    const int nb = n0 + wn * 64 + l15;
#pragma unroll
    for (int fm = 0; fm < 4; fm++)
#pragma unroll
        for (int fn = 0; fn < 4; fn++)
#pragma unroll
            for (int r = 0; r < 4; r++)
                out[(size_t)(mb + fm * 16 + r) * HIDDEN + nb + fn * 16] =
                    acc[fm][fn][r] + bcolv[fn];
}

// ==================== RoPE + pack to bf16 (Q scaled by 1/sqrt(HD)) ===========
__global__ void k_rope_pack(const float* __restrict__ q, const float* __restrict__ k,
                            const float* __restrict__ ct, const float* __restrict__ st,
                            ushort_t* __restrict__ Qb, ushort_t* __restrict__ Kb) {
    int idx = blockIdx.x * 256 + threadIdx.x;   // exactly NB*NH*SEQ*64 threads
    int d = idx & 63;
    int s = (idx >> 6) & (SEQ - 1);
    int bh = idx >> 17;
    size_t base = ((size_t)bh * SEQ + s) * HD;
    float c = ct[(s << 6) + d], sn = st[(s << 6) + d];
    const float scq = 0.08838834764831845f;
    float q0 = q[base + d], q1 = q[base + d + 64];
    Qb[base + d]      = bf16r((q0 * c - q1 * sn) * scq);
    Qb[base + d + 64] = bf16r((q1 * c + q0 * sn) * scq);
    float k0 = k[base + d], k1 = k[base + d + 64];
    Kb[base + d]      = bf16r(k0 * c - k1 * sn);
    Kb[base + d + 64] = bf16r(k1 * c + k0 * sn);
}

// ==================== V transpose + pack: (B,H,S,D) fp32 -> (B,H,D,S) bf16 ===
__global__ __launch_bounds__(256)
void k_vpack(const float* __restrict__ v, ushort_t* __restrict__ vt) {
    __shared__ float t[64][65];
    const int tid = threadIdx.x;
    const int bh = blockIdx.z;
    const int s0 = blockIdx.x << 6;
    const int d0 = blockIdx.y << 6;
    const float* src = v + ((size_t)bh * SEQ + s0) * HD + d0;
    const int rr = tid >> 4;
    const int cc = (tid & 15) << 2;
#pragma unroll
    for (int i = 0; i < 4; i++) {
        float4 x = *(const float4*)(src + (size_t)(i * 16 + rr) * HD + cc);
        t[i * 16 + rr][cc] = x.x;
        t[i * 16 + rr][cc + 1] = x.y;
        t[i * 16 + rr][cc + 2] = x.z;
        t[i * 16 + rr][cc + 3] = x.w;
    }
    __syncthreads();
    const int dr = tid >> 2;
    const int sc_ = (tid & 3) << 4;
    ushort_t* dst = vt + ((size_t)bh * HD + d0 + dr) * SEQ + s0 + sc_;
    u16x8 o0, o1;
#pragma unroll
    for (int u = 0; u < 8; u++) o0[u] = bf16r(t[sc_ + u][dr]);
#pragma unroll
    for (int u = 0; u < 8; u++) o1[u] = bf16r(t[sc_ + 8 + u][dr]);
    *(u16x8*)dst = o0;
    *(u16x8*)(dst + 8) = o1;
}

// ==================== MFMA flash attention v4 ================================
__global__ __launch_bounds__(256, 2)
void k_flash_mfma(const ushort_t* __restrict__ Qb, const ushort_t* __restrict__ Kb,
                  const ushort_t* __restrict__ Vt,
                  ushort_t* __restrict__ ch, ushort_t* __restrict__ cl) {
    __shared__ ushort_t KV[128 * 136];
    __shared__ ushort_t Ps[128 * 136];
    const int tid = threadIdx.x;
    const int lane = tid & 63;
    const int w = tid >> 6;
    const int quad = lane >> 4;
    const int l15 = lane & 15;
    const int bi = blockIdx.x;
    const int bh = bi & 31;              // XCD swizzle: bh%8 == XCD id
    const int qt = bi >> 5;              // 0..15 (128 q rows each)
    const ushort_t* Qg = Qb + ((size_t)bh * SEQ + ((size_t)qt << 7)) * HD;
    const ushort_t* Kg = Kb + (size_t)bh * SEQ * HD;
    const ushort_t* Vg = Vt + (size_t)bh * HD * SEQ;

    // persistent Q fragments (B-operand): rows w*32+qi*16+l15, k = ks*32+quad*8
    bf16x8 qf[2][4];
#pragma unroll
    for (int qi = 0; qi < 2; qi++)
#pragma unroll
        for (int ks = 0; ks < 4; ks++)
            qf[qi][ks] = *(const bf16x8*)(Qg + (size_t)(w * 32 + qi * 16 + l15) * HD + ks * 32 + quad * 8);

    const int sr = tid >> 4;            // staging row 0..15
    const int sc8 = (tid & 15) << 3;    // staging col (8 elems = 16B)

    // prefetch chunk 0 K and V^T into registers
    u16x8 Kreg[8], Vreg[8];
#pragma unroll
    for (int i = 0; i < 8; i++)
        Kreg[i] = *(const u16x8*)(Kg + (size_t)(i * 16 + sr) * HD + sc8);
#pragma unroll
    for (int i = 0; i < 8; i++)
        Vreg[i] = *(const u16x8*)(Vg + (size_t)(i * 16 + sr) * SEQ + sc8);

    f32x4 acc[2][8];
#pragma unroll
    for (int qi = 0; qi < 2; qi++)
#pragma unroll
        for (int d = 0; d < 8; d++) acc[qi][d] = (f32x4){0.f, 0.f, 0.f, 0.f};
    float lp[2] = {0.f, 0.f};

    for (int kt = 0; kt < SEQ; kt += 128) {
        const int np = kt + 128;
        __syncthreads();                // prev PV reads of KV done
#pragma unroll
        for (int i = 0; i < 8; i++)     // stage K_i; refill Kreg = K_{i+1}
            *(u16x8*)&KV[(i * 16 + sr) * 136 + sc8] = Kreg[i];
        if (np < SEQ) {
#pragma unroll
            for (int i = 0; i < 8; i++)
                Kreg[i] = *(const u16x8*)(Kg + (size_t)(np + i * 16 + sr) * HD + sc8);
        }
        __syncthreads();

        // ---- scores transposed: sc[qi][j] = K(16 rows) x Q(16 rows)^T ----
        f32x4 sc[2][8];
#pragma unroll
        for (int qi = 0; qi < 2; qi++)
#pragma unroll
            for (int j = 0; j < 8; j++) sc[qi][j] = (f32x4){0.f, 0.f, 0.f, 0.f};
#pragma unroll
        for (int ks = 0; ks < 4; ks++) {
#pragma unroll
            for (int jh = 0; jh < 2; jh++) {
                bf16x8 kf[4];
#pragma unroll
                for (int j = 0; j < 4; j++)
                    kf[j] = *(const bf16x8*)&KV[((jh * 4 + j) * 16 + l15) * 136 + ks * 32 + quad * 8];
#pragma unroll
                for (int qi = 0; qi < 2; qi++)
#pragma unroll
                    for (int j = 0; j < 4; j++)
                        sc[qi][jh * 4 + j] = __builtin_amdgcn_mfma_f32_16x16x32_bf16(
                            kf[j], qf[qi][ks], sc[qi][jh * 4 + j], 0, 0, 0);
            }
        }

        // ---- p = exp(score); accumulate l; write P (8B contiguous) ----
#pragma unroll
        for (int qi = 0; qi < 2; qi++) {
            const int prow = (w * 32 + qi * 16 + l15) * 136 + quad * 4;
#pragma unroll
            for (int j = 0; j < 8; j++) {
                float p0 = __expf(sc[qi][j][0]);
                float p1 = __expf(sc[qi][j][1]);
                float p2 = __expf(sc[qi][j][2]);
                float p3 = __expf(sc[qi][j][3]);
                lp[qi] += (p0 + p1) + (p2 + p3);
                __hip_bfloat162 lo2 = __float22bfloat162_rn({p0, p1});
                __hip_bfloat162 hi2 = __float22bfloat162_rn({p2, p3});
                uint2 pk = make_uint2(*(u32*)&lo2, *(u32*)&hi2);
                *(uint2*)&Ps[prow + j * 16] = pk;
            }
        }
        __syncthreads();                // kf reads done + Ps visible
#pragma unroll
        for (int i = 0; i < 8; i++)     // stage V_i; refill Vreg = V_{i+1}
            *(u16x8*)&KV[(i * 16 + sr) * 136 + sc8] = Vreg[i];
        if (np < SEQ) {
#pragma unroll
            for (int i = 0; i < 8; i++)
                Vreg[i] = *(const u16x8*)(Vg + (size_t)(i * 16 + sr) * SEQ + np + sc8);
        }
        __syncthreads();

        // ---- PV transposed: acc[qi][db] = V^T(16 d-rows) x P^T ----
#pragma unroll
        for (int ks = 0; ks < 4; ks++) {
            bf16x8 pf[2];
#pragma unroll
            for (int qi = 0; qi < 2; qi++)
                pf[qi] = *(const bf16x8*)&Ps[(w * 32 + qi * 16 + l15) * 136 + ks * 32 + quad * 8];
#pragma unroll
            for (int db = 0; db < 8; db++) {
                bf16x8 vf = *(const bf16x8*)&KV[(db * 16 + l15) * 136 + ks * 32 + quad * 8];
#pragma unroll
                for (int qi = 0; qi < 2; qi++)
                    acc[qi][db] = __builtin_amdgcn_mfma_f32_16x16x32_bf16(vf, pf[qi], acc[qi][db], 0, 0, 0);
            }
        }
    }

    // ---- epilogue: l-reduce, normalize, re-layout via Ps, coalesced store ----
    float inv[2];
#pragma unroll
    for (int qi = 0; qi < 2; qi++) {
        float l = lp[qi];
        l += __shfl_xor(l, 16);
        l += __shfl_xor(l, 32);
        inv[qi] = 1.0f / l;
    }
    const size_t obase = ((size_t)bh * SEQ + ((size_t)qt << 7)) * HD;

    __syncthreads();                    // final PV pf reads of Ps done
    // hi pass
#pragma unroll
    for (int qi = 0; qi < 2; qi++)
#pragma unroll
        for (int db = 0; db < 8; db++) {
            ushort4 hh;
            ushort_t dum;
            split1(acc[qi][db][0] * inv[qi], hh.x, dum);
            split1(acc[qi][db][1] * inv[qi], hh.y, dum);
            split1(acc[qi][db][2] * inv[qi], hh.z, dum);
            split1(acc[qi][db][3] * inv[qi], hh.w, dum);
            *(ushort4*)&Ps[(w * 32 + qi * 16 + l15) * 136 + db * 16 + quad * 4] = hh;
        }
    __syncthreads();
#pragma unroll
    for (int t = 0; t < 8; t++) {
        int c = t * 256 + tid;
        int row = c >> 4, col8 = (c & 15) << 3;
        *(u16x8*)&ch[obase + (size_t)row * HD + col8] = *(const u16x8*)&Ps[row * 136 + col8];
    }
    __syncthreads();
    // lo pass
#pragma unroll
    for (int qi = 0; qi < 2; qi++)
#pragma unroll
        for (int db = 0; db < 8; db++) {
            ushort4 ll;
            ushort_t dum;
            split1(acc[qi][db][0] * inv[qi], dum, ll.x);
            split1(acc[qi][db][1] * inv[qi], dum, ll.y);
            split1(acc[qi][db][2] * inv[qi], dum, ll.z);
            split1(acc[qi][db][3] * inv[qi], dum, ll.w);
            *(ushort4*)&Ps[(w * 32 + qi * 16 + l15) * 136 + db * 16 + quad * 4] = ll;
        }
    __syncthreads();
#pragma unroll
    for (int t = 0; t < 8; t++) {
        int c = t * 256 + tid;
        int row = c >> 4, col8 = (c & 15) << 3;
        *(u16x8*)&cl[obase + (size_t)row * HD + col8] = *(const u16x8*)&Ps[row * 136 + col8];
    }
}

// ==================== launch =================================================
extern "C" void kernel_launch(void* const* d_in, const int* in_sizes, int n_in,
                              void* d_out, int out_size, void* d_ws, size_t ws_size,
                              hipStream_t stream) {
    const float* X  = (const float*)d_in[0];
    const float* Wq = (const float*)d_in[1];
    const float* bq = (const float*)d_in[2];
    const float* Wk = (const float*)d_in[3];
    const float* bk = (const float*)d_in[4];
    const float* Wv = (const float*)d_in[5];
    const float* bv = (const float*)d_in[6];
    const float* Wo = (const float*)d_in[7];
    const float* bo = (const float*)d_in[8];
    float* out = (float*)d_out;

    const size_t QS = (size_t)NB * NH * SEQ * HD;   // 8,388,608 elems
    const size_t WS = (size_t)HIDDEN * HIDDEN;      // 4,194,304 elems
    float* q_ws = (float*)d_ws;
    float* k_ws = q_ws + QS;
    float* v_ws = k_ws + QS;
    float* cost = v_ws + QS;
    float* sint = cost + (size_t)SEQ * 64;
    ushort_t* Xh = (ushort_t*)(sint + (size_t)SEQ * 64);  // -> Qb after QKV
    ushort_t* Wh0 = Xh + QS;
    ushort_t* Wh1 = Wh0 + WS;
    ushort_t* Wh2 = Wh1 + WS;
    ushort_t* Woh = Wh2 + WS;
    ushort_t* Wol = Woh + WS;
    ushort_t* Kb  = Wol + WS;
    ushort_t* Vtb = Kb + QS;
    ushort_t* ctxh = (ushort_t*)q_ws;                     // blocked ctx over dead q_ws
    ushort_t* ctxl = ctxh + QS;

    k_rope_tables<<<(SEQ * 64) / 256, 256, 0, stream>>>(cost, sint);

    k_cvt_all<<<(XG + 3 * WG) / 256, 256, 0, stream>>>(
        (const float4*)X, (const float4*)Wq, (const float4*)Wk, (const float4*)Wv,
        (ushort4*)Xh, (ushort4*)Wh0, (ushort4*)Wh1, (ushort4*)Wh2);
    k_split<<<WS / 4 / 256, 256, 0, stream>>>((const float4*)Wo, (ushort4*)Woh, (ushort4*)Wol);

    k_gemm_qkv8<<<384, 512, 0, stream>>>(Xh, Wh0, Wh1, Wh2, bq, bk, bv,
                                         q_ws, k_ws, v_ws);

    ushort_t* Qbb = Xh;   // X bf16 dead after QKV GEMM
    k_rope_pack<<<(NB * NH * SEQ * 64) / 256, 256, 0, stream>>>(q_ws, k_ws, cost, sint, Qbb, Kb);
    k_vpack<<<dim3(SEQ / 64, HD / 64, NB * NH), 256, 0, stream>>>(v_ws, Vtb);

    k_flash_mfma<<<512, 256, 0, stream>>>(Qbb, Kb, Vtb, ctxh, ctxl);

    k_gemm_o2<<<256, 512, 0, stream>>>(ctxh, ctxl, Woh, Wol, bo, out);
}

// Round 7
// 501.688 us; speedup vs baseline: 1.0241x; 1.0241x over previous
//
#include <hip/hip_runtime.h>
#include <hip/hip_bf16.h>
#include <math.h>

#define HIDDEN 2048
#define NH 16
#define HD 128
#define NB 2
#define SEQ 2048
#define K_DIM 2048

typedef unsigned int u32;
typedef unsigned short ushort_t;
typedef __bf16 bf16x8 __attribute__((ext_vector_type(8)));
typedef float f32x4 __attribute__((ext_vector_type(4)));
typedef ushort_t u16x8 __attribute__((ext_vector_type(8)));

// ---------- fp32 -> (bf16 hi, bf16 lo) split, RNE both halves ----------
__device__ __forceinline__ void split1(float x, unsigned short& h, unsigned short& l) {
    u32 u = __float_as_uint(x);
    u32 hr = (u + 0x7FFFu + ((u >> 16) & 1u)) >> 16;
    h = (unsigned short)hr;
    float r = x - __uint_as_float(hr << 16);
    u32 u2 = __float_as_uint(r);
    l = (unsigned short)((u2 + 0x7FFFu + ((u2 >> 16) & 1u)) >> 16);
}

__device__ __forceinline__ ushort_t bf16r(float x) {
    u32 u = __float_as_uint(x);
    return (ushort_t)((u + 0x7FFFu + ((u >> 16) & 1u)) >> 16);
}

__device__ __forceinline__ float bf2f(ushort_t u) {
    return __uint_as_float(((u32)u) << 16);
}

__device__ __forceinline__ void gl_lds16(const void* g, void* l) {
    __builtin_amdgcn_global_load_lds(
        (const __attribute__((address_space(1))) u32*)g,
        (__attribute__((address_space(3))) u32*)l, 16, 0, 0);
}

// ==================== RoPE tables (double-precision trig) ====================
__global__ void k_rope_tables(float* __restrict__ ct, float* __restrict__ st) {
    int idx = blockIdx.x * 256 + threadIdx.x;   // exactly SEQ*64 threads
    int s = idx >> 6, d = idx & 63;
    double inv = pow(10000.0, -(double)d * (1.0 / 64.0));
    double ang = (double)s * inv;
    ct[idx] = (float)cos(ang);
    st[idx] = (float)sin(ang);
}

// ========== fused fp32->bf16: X,Wq,Wk,Wv (hi) + Wo (hi/lo split) =============
#define XG 2097152   // X float4 groups
#define WG 1048576   // W float4 groups
__global__ void k_cvt_all(const float4* __restrict__ X, const float4* __restrict__ W0,
                          const float4* __restrict__ W1, const float4* __restrict__ W2,
                          const float4* __restrict__ Wo,
                          ushort4* __restrict__ Xh, ushort4* __restrict__ H0,
                          ushort4* __restrict__ H1, ushort4* __restrict__ H2,
                          ushort4* __restrict__ WoH, ushort4* __restrict__ WoL) {
    int idx = blockIdx.x * 256 + threadIdx.x;   // XG + 4*WG threads
    if (idx < XG + 3 * WG) {
        const float4* src;
        ushort4* dst;
        int off;
        if (idx < XG) { src = X; dst = Xh; off = idx; }
        else {
            int t = idx - XG;
            int m = t >> 20;        // WG = 2^20
            off = t & (WG - 1);
            src = (m == 0) ? W0 : (m == 1) ? W1 : W2;
            dst = (m == 0) ? H0 : (m == 1) ? H1 : H2;
        }
        float4 x = src[off];
        ushort4 h;
        h.x = bf16r(x.x); h.y = bf16r(x.y); h.z = bf16r(x.z); h.w = bf16r(x.w);
        dst[off] = h;
    } else {
        int off = idx - XG - 3 * WG;
        float4 x = Wo[off];
        ushort4 h, l;
        split1(x.x, h.x, l.x);
        split1(x.y, h.y, l.y);
        split1(x.z, h.z, l.z);
        split1(x.w, h.w, l.w);
        WoH[off] = h;
        WoL[off] = l;
    }
}

// ==================== common waitcnt/barrier macros ==========================
#define BAR  __builtin_amdgcn_s_barrier()
#define VM6  asm volatile("s_waitcnt vmcnt(6)" ::: "memory")
#define VM4  asm volatile("s_waitcnt vmcnt(4)" ::: "memory")
#define VM0  asm volatile("s_waitcnt vmcnt(0)" ::: "memory")
#define PRIO1 __builtin_amdgcn_s_setprio(1)
#define PRIO0 __builtin_amdgcn_s_setprio(0)

// ==================== fused QKV: 256x256, BK=32, 4-slot rotation =============
// R5 schedule (verified): phase p = {STAGE(tile p+2 -> slot (p+2)&3); VM4;
// BAR_p; RD(tile p+1 -> other reg set); MFMA(tile p on current set)}.
// Invariant A (gate): VM4 pre-BAR -> at BAR_p every wave certified its
// tile-(p+1) loads complete. Invariant B: stage@p targets slot of tile p-2,
// reads drained by MFMA@p-1 before BAR_{p-1} < overwrite issue. S=4 >= L+2.
// Epilogue writes bf16 directly (halves write traffic vs fp32).
#define QSTAGE(slot, kt) do { \
    const ushort_t* gA_ = Xh + sgA + (size_t)(kt) * 32; \
    gl_lds16(gA_, &As[slot][(w * 32) * 32]); \
    gl_lds16(gA_ + 16 * 2048, &As[slot][(w * 32 + 16) * 32]); \
    const ushort_t* gB_ = Wsel + sgB + (size_t)(kt) * 32; \
    gl_lds16(gB_, &Bs[slot][(w * 32) * 32]); \
    gl_lds16(gB_ + 16 * 2048, &Bs[slot][(w * 32 + 16) * 32]); \
} while (0)

#define QRD(AD, BD, slot) do { \
    _Pragma("unroll") for (int mf = 0; mf < 8; mf++) \
        AD[mf] = *(const bf16x8*)&As[slot][arow + mf * 512 + ccq]; \
    _Pragma("unroll") for (int nf = 0; nf < 4; nf++) \
        BD[nf] = *(const bf16x8*)&Bs[slot][brow + nf * 512 + ccq]; \
} while (0)

#define QMFMA(AD, BD) do { PRIO1; \
    _Pragma("unroll") for (int mf = 0; mf < 8; mf++) \
    _Pragma("unroll") for (int nf = 0; nf < 4; nf++) \
        acc[mf][nf] = __builtin_amdgcn_mfma_f32_16x16x32_bf16( \
            AD[mf], BD[nf], acc[mf][nf], 0, 0, 0); \
    PRIO0; } while (0)

__global__ __launch_bounds__(512, 2)
void k_gemm_qkv8(const ushort_t* __restrict__ Xh,
                 const ushort_t* __restrict__ W0, const ushort_t* __restrict__ W1,
                 const ushort_t* __restrict__ W2,
                 const float* __restrict__ b0, const float* __restrict__ b1,
                 const float* __restrict__ b2,
                 ushort_t* __restrict__ o0, ushort_t* __restrict__ o1,
                 ushort_t* __restrict__ o2) {
    __shared__ ushort_t As[4][256 * 32];
    __shared__ ushort_t Bs[4][256 * 32];
    const int tid = threadIdx.x;
    const int lane = tid & 63;
    const int w = tid >> 6;        // wave 0..7
    const int wm = w >> 2;         // 0..1  (128 output rows each)
    const int wn = w & 3;          // 0..3  (64 output cols each)
    const int quad = lane >> 4;
    const int l15 = lane & 15;

    // bijective XCD swizzle (384 % 8 == 0)
    int bid = blockIdx.x;
    bid = (bid & 7) * 48 + (bid >> 3);
    const int bx = bid & 15;       // m-block
    const int by = bid >> 4;       // 0..23
    const int m0 = bx << 8;
    const int mat = by >> 3;
    const int n0 = (by & 7) << 8;
    const ushort_t* Wsel = (mat == 0) ? W0 : (mat == 1) ? W1 : W2;
    const float* bias = (mat == 0) ? b0 : (mat == 1) ? b1 : b2;
    ushort_t* out = (mat == 0) ? o0 : (mat == 1) ? o1 : o2;

    // staging: wave w covers rows [w*32, w*32+32); lane -> (row lrow4, slot
    // lane&3); global col slot pre-swizzled.
    const int lrow4 = lane >> 2;
    const int col8 = (((lane & 3) ^ ((lrow4 >> 1) & 3)) << 3);
    const size_t sgA = (size_t)(m0 + w * 32 + lrow4) * 2048 + col8;
    const size_t sgB = (size_t)(n0 + w * 32 + lrow4) * 2048 + col8;

    // fragment reads: row R wants global slot q -> LDS slot q^((R>>1)&3)
    const int arow = (wm * 128 + l15) * 32;
    const int brow = (wn * 64 + l15) * 32;
    const int ccq = ((quad ^ ((l15 >> 1) & 3)) << 3);

    f32x4 acc[8][4];
#pragma unroll
    for (int i = 0; i < 8; i++)
#pragma unroll
        for (int j = 0; j < 4; j++) acc[i][j] = (f32x4){0.f, 0.f, 0.f, 0.f};

    bf16x8 aA[8], bA[4], aB[8], bB[4];

    // prologue: tiles 0,1 staged; VM4 pre-BAR certifies tile0 for all waves
    QSTAGE(0, 0); QSTAGE(1, 1);
    VM4; BAR;
    QRD(aA, bA, 0);

    // phases 0..59 (15 iters x 4 phases; slots compile-time constants)
    for (int p = 0; p < 60; p += 4) {
        QSTAGE(2, p + 2); VM4; BAR; QRD(aB, bB, 1); QMFMA(aA, bA);   // tile p
        QSTAGE(3, p + 3); VM4; BAR; QRD(aA, bA, 2); QMFMA(aB, bB);   // tile p+1
        QSTAGE(0, p + 4); VM4; BAR; QRD(aB, bB, 3); QMFMA(aA, bA);   // tile p+2
        QSTAGE(1, p + 5); VM4; BAR; QRD(aA, bA, 0); QMFMA(aB, bB);   // tile p+3
    }
    // tail phases 60..63
    QSTAGE(2, 62); VM4; BAR; QRD(aB, bB, 1); QMFMA(aA, bA);          // tile 60
    QSTAGE(3, 63); VM4; BAR; QRD(aA, bA, 2); QMFMA(aB, bB);          // tile 61
    VM0; BAR;                QRD(aB, bB, 3); QMFMA(aA, bA);          // tile 62
    QMFMA(aB, bB);                                                   // tile 63

    // ---- epilogue: bias + bf16 store to blocked (B,NH,S,HD) ----
    float bcolv[4];
#pragma unroll
    for (int nf = 0; nf < 4; nf++) bcolv[nf] = bias[n0 + wn * 64 + nf * 16 + l15];

    const int mbase = m0 + wm * 128 + quad * 4;
#pragma unroll
    for (int mf = 0; mf < 8; mf++)
#pragma unroll
        for (int nf = 0; nf < 4; nf++) {
            const int n = n0 + wn * 64 + nf * 16 + l15;
            const int hh = n >> 7;
            const int d = n & 127;
#pragma unroll
            for (int r = 0; r < 4; r++) {
                const int m = mbase + mf * 16 + r;
                const int bb = m >> 11;
                const int s = m & (SEQ - 1);
                out[((size_t)(bb * NH + hh) * SEQ + s) * HD + d] =
                    bf16r(acc[mf][nf][r] + bcolv[nf]);
            }
        }
}

// ==================== O-projection: 256x128, BK=32, 3-slot rotation ==========
// R5 schedule (verified): phase q = {VM0; BAR_q; STAGE(tile q+2 ->
// slot (q+2)%3); RD(tile q+1 <- slot (q+1)%3); MFMA(tile q)}.
// Invariant A: tile q+1 staged @ q-1 post-BAR_{q-1}; VM0@q pre-BAR drains
// per-wave -> certified globally at BAR_q (loads ~1 MFMA phase old).
// Invariant B: slot (q+2)%3 holds tile q-1, reads drained by MFMA@q-1 in
// [BAR_{q-1}, BAR_q]; overwrite DMA issues post-BAR_q.
#define OSTAGE(slot, kt) do { \
    const size_t koA = (size_t)((kt) >> 2) * ((size_t)SEQ * HD) + (size_t)((kt) & 3) * 32; \
    const size_t koB = (size_t)(kt) * 32; \
    gl_lds16(Ah + sgA0 + koA, &Ah_s[slot][(w * 32) * 32]); \
    gl_lds16(Ah + sgA0 + 16 * HD + koA, &Ah_s[slot][(w * 32 + 16) * 32]); \
    gl_lds16(Al + sgA0 + koA, &Al_s[slot][(w * 32) * 32]); \
    gl_lds16(Al + sgA0 + 16 * HD + koA, &Al_s[slot][(w * 32 + 16) * 32]); \
    gl_lds16(Bh + sgB0 + koB, &Bh_s[slot][(w * 16) * 32]); \
    gl_lds16(Bl + sgB0 + koB, &Bl_s[slot][(w * 16) * 32]); \
} while (0)

#define ORD(AH, AL, BH, BL, slot) do { \
    _Pragma("unroll") for (int f = 0; f < 4; f++) { \
        AH[f] = *(const bf16x8*)&Ah_s[slot][aro + f * 512 + cco]; \
        AL[f] = *(const bf16x8*)&Al_s[slot][aro + f * 512 + cco]; \
        BH[f] = *(const bf16x8*)&Bh_s[slot][bro + f * 512 + cco]; \
        BL[f] = *(const bf16x8*)&Bl_s[slot][bro + f * 512 + cco]; \
    } \
} while (0)

#define OMFMA(AH, AL, BH, BL) do { PRIO1; \
    _Pragma("unroll") for (int mf = 0; mf < 4; mf++) \
    _Pragma("unroll") for (int nf = 0; nf < 4; nf++) { \
        acc[mf][nf] = __builtin_amdgcn_mfma_f32_16x16x32_bf16( \
            AH[mf], BH[nf], acc[mf][nf], 0, 0, 0); \
        acc[mf][nf] = __builtin_amdgcn_mfma_f32_16x16x32_bf16( \
            AH[mf], BL[nf], acc[mf][nf], 0, 0, 0); \
        acc[mf][nf] = __builtin_amdgcn_mfma_f32_16x16x32_bf16( \
            AL[mf], BH[nf], acc[mf][nf], 0, 0, 0); \
    } PRIO0; } while (0)

__global__ __launch_bounds__(512, 2)
void k_gemm_o2(const ushort_t* __restrict__ Ah, const ushort_t* __restrict__ Al,
               const ushort_t* __restrict__ Bh, const ushort_t* __restrict__ Bl,
               const float* __restrict__ bias, float* __restrict__ out) {
    __shared__ ushort_t Ah_s[3][256 * 32];
    __shared__ ushort_t Al_s[3][256 * 32];
    __shared__ ushort_t Bh_s[3][128 * 32];
    __shared__ ushort_t Bl_s[3][128 * 32];
    const int tid = threadIdx.x;
    const int lane = tid & 63;
    const int w = tid >> 6;        // wave 0..7
    const int wm = w >> 1;         // 0..3 (64 output rows each)
    const int wn = w & 1;          // 0..1 (64 output cols each)
    const int quad = lane >> 4;
    const int l15 = lane & 15;

    // bijective XCD swizzle (256 % 8 == 0)
    int bid = blockIdx.x;
    bid = (bid & 7) * 32 + (bid >> 3);
    const int bx = bid & 15;       // m-block (0..15)
    const int by = bid >> 4;       // n-block (0..15)
    const int m0 = bx << 8;        // 256 rows
    const int n0 = by << 7;        // 128 cols

    // staging addressing (pre-swizzled global col slot, (r>>1)&3 XOR)
    const int lrow4 = lane >> 2;
    const int col8 = (((lane & 3) ^ ((lrow4 >> 1) & 3)) << 3);
    const size_t sgA0 = ((size_t)(m0 >> 11) * NH * SEQ + (size_t)((m0 & (SEQ - 1)) + w * 32 + lrow4)) * HD + col8;
    const size_t sgB0 = (size_t)(n0 + w * 16 + lrow4) * K_DIM + col8;

    // fragment reads
    const int aro = (wm * 64 + l15) * 32;
    const int bro = (wn * 64 + l15) * 32;
    const int cco = ((quad ^ ((l15 >> 1) & 3)) << 3);

    f32x4 acc[4][4];
#pragma unroll
    for (int i = 0; i < 4; i++)
#pragma unroll
        for (int j = 0; j < 4; j++) acc[i][j] = (f32x4){0.f, 0.f, 0.f, 0.f};

    bf16x8 ahA[4], alA[4], bhA[4], blA[4];
    bf16x8 ahB[4], alB[4], bhB[4], blB[4];

    // prologue: tiles 0,1 staged; VM6 pre-BAR certifies tile0 for all waves
    OSTAGE(0, 0);
    OSTAGE(1, 1);
    VM6; BAR;
    ORD(ahA, alA, bhA, blA, 0);

    // phases 0..59 (10 iters x 6 phases; slot/set pattern period 6)
    for (int it = 0; it < 10; ++it) {
        const int q = 6 * it;
        VM0; BAR; OSTAGE(2, q + 2); ORD(ahB, alB, bhB, blB, 1); OMFMA(ahA, alA, bhA, blA);  // tile q
        VM0; BAR; OSTAGE(0, q + 3); ORD(ahA, alA, bhA, blA, 2); OMFMA(ahB, alB, bhB, blB);  // q+1
        VM0; BAR; OSTAGE(1, q + 4); ORD(ahB, alB, bhB, blB, 0); OMFMA(ahA, alA, bhA, blA);  // q+2
        VM0; BAR; OSTAGE(2, q + 5); ORD(ahA, alA, bhA, blA, 1); OMFMA(ahB, alB, bhB, blB);  // q+3
        VM0; BAR; OSTAGE(0, q + 6); ORD(ahB, alB, bhB, blB, 2); OMFMA(ahA, alA, bhA, blA);  // q+4
        VM0; BAR; OSTAGE(1, q + 7); ORD(ahA, alA, bhA, blA, 0); OMFMA(ahB, alB, bhB, blB);  // q+5
    }
    // tail phases 60..63
    VM0; BAR; OSTAGE(2, 62); ORD(ahB, alB, bhB, blB, 1); OMFMA(ahA, alA, bhA, blA);  // tile 60
    VM0; BAR; OSTAGE(0, 63); ORD(ahA, alA, bhA, blA, 2); OMFMA(ahB, alB, bhB, blB);  // tile 61
    VM0; BAR;                ORD(ahB, alB, bhB, blB, 0); OMFMA(ahA, alA, bhA, blA);  // tile 62
    OMFMA(ahB, alB, bhB, blB);                                                        // tile 63

    // ---- epilogue: bias + coalesced fp32 store ----
    float bcolv[4];
#pragma unroll
    for (int nf = 0; nf < 4; nf++) bcolv[nf] = bias[n0 + wn * 64 + nf * 16 + l15];

    const int mb = m0 + wm * 64 + quad * 4;
    const int nb = n0 + wn * 64 + l15;
#pragma unroll
    for (int fm = 0; fm < 4; fm++)
#pragma unroll
        for (int fn = 0; fn < 4; fn++)
#pragma unroll
            for (int r = 0; r < 4; r++)
                out[(size_t)(mb + fm * 16 + r) * HIDDEN + nb + fn * 16] =
                    acc[fm][fn][r] + bcolv[fn];
}

// ========== fused RoPE-pack (bf16 in) + V transpose-pack (bf16 in) ===========
// blocks [0, 16384): RoPE on qb/kb (blocked bf16) -> Qb (scaled) / Kb
//   (NB*NH*SEQ*64 = 4,194,304 threads; R6 bug was 8192 blocks = half coverage)
// blocks [16384, 18432): V transpose (B,H,S,D) bf16 -> (B,H,D,S) bf16
__global__ __launch_bounds__(256)
void k_rope_vpack(const ushort_t* __restrict__ qb, const ushort_t* __restrict__ kb,
                  const ushort_t* __restrict__ vb,
                  const float* __restrict__ ct, const float* __restrict__ st,
                  ushort_t* __restrict__ Qb, ushort_t* __restrict__ Kb,
                  ushort_t* __restrict__ vt) {
    __shared__ float t[64][65];
    const int tid = threadIdx.x;
    const int blk = blockIdx.x;
    if (blk < 16384) {
        // ---- RoPE path ----
        int idx = blk * 256 + tid;          // NB*NH*SEQ*64 threads
        int d = idx & 63;
        int s = (idx >> 6) & (SEQ - 1);
        int bh = idx >> 17;                 // 0..31
        size_t base = ((size_t)bh * SEQ + s) * HD;
        float c = ct[(s << 6) + d], sn = st[(s << 6) + d];
        const float scq = 0.08838834764831845f;
        float q0 = bf2f(qb[base + d]), q1 = bf2f(qb[base + d + 64]);
        Qb[base + d]      = bf16r((q0 * c - q1 * sn) * scq);
        Qb[base + d + 64] = bf16r((q1 * c + q0 * sn) * scq);
        float k0 = bf2f(kb[base + d]), k1 = bf2f(kb[base + d + 64]);
        Kb[base + d]      = bf16r(k0 * c - k1 * sn);
        Kb[base + d + 64] = bf16r(k1 * c + k0 * sn);
    } else {
        // ---- V transpose path ----
        int b = blk - 16384;                // 2048 blocks: (32 s, 2 d, 32 bh)
        const int s0 = (b & 31) << 6;
        const int d0 = ((b >> 5) & 1) << 6;
        const int bh = b >> 6;
        const ushort_t* src = vb + ((size_t)bh * SEQ + s0) * HD + d0;
        const int rr = tid >> 4;
        const int cc = (tid & 15) << 2;
#pragma unroll
        for (int i = 0; i < 4; i++) {
            ushort4 x = *(const ushort4*)(src + (size_t)(i * 16 + rr) * HD + cc);
            t[i * 16 + rr][cc]     = bf2f(x.x);
            t[i * 16 + rr][cc + 1] = bf2f(x.y);
            t[i * 16 + rr][cc + 2] = bf2f(x.z);
            t[i * 16 + rr][cc + 3] = bf2f(x.w);
        }
        __syncthreads();
        const int dr = tid >> 2;
        const int sc_ = (tid & 3) << 4;
        ushort_t* dst = vt + ((size_t)bh * HD + d0 + dr) * SEQ + s0 + sc_;
        u16x8 o0, o1;
#pragma unroll
        for (int u = 0; u < 8; u++) o0[u] = bf16r(t[sc_ + u][dr]);
#pragma unroll
        for (int u = 0; u < 8; u++) o1[u] = bf16r(t[sc_ + 8 + u][dr]);
        *(u16x8*)dst = o0;
        *(u16x8*)(dst + 8) = o1;
    }
}

// ==================== MFMA flash attention v4 ================================
__global__ __launch_bounds__(256, 2)
void k_flash_mfma(const ushort_t* __restrict__ Qb, const ushort_t* __restrict__ Kb,
                  const ushort_t* __restrict__ Vt,
                  ushort_t* __restrict__ ch, ushort_t* __restrict__ cl) {
    __shared__ ushort_t KV[128 * 136];
    __shared__ ushort_t Ps[128 * 136];
    const int tid = threadIdx.x;
    const int lane = tid & 63;
    const int w = tid >> 6;
    const int quad = lane >> 4;
    const int l15 = lane & 15;
    const int bi = blockIdx.x;
    const int bh = bi & 31;              // XCD swizzle: bh%8 == XCD id
    const int qt = bi >> 5;              // 0..15 (128 q rows each)
    const ushort_t* Qg = Qb + ((size_t)bh * SEQ + ((size_t)qt << 7)) * HD;
    const ushort_t* Kg = Kb + (size_t)bh * SEQ * HD;
    const ushort_t* Vg = Vt + (size_t)bh * HD * SEQ;

    // persistent Q fragments (B-operand): rows w*32+qi*16+l15, k = ks*32+quad*8
    bf16x8 qf[2][4];
#pragma unroll
    for (int qi = 0; qi < 2; qi++)
#pragma unroll
        for (int ks = 0; ks < 4; ks++)
            qf[qi][ks] = *(const bf16x8*)(Qg + (size_t)(w * 32 + qi * 16 + l15) * HD + ks * 32 + quad * 8);

    const int sr = tid >> 4;            // staging row 0..15
    const int sc8 = (tid & 15) << 3;    // staging col (8 elems = 16B)

    // prefetch chunk 0 K and V^T into registers
    u16x8 Kreg[8], Vreg[8];
#pragma unroll
    for (int i = 0; i < 8; i++)
        Kreg[i] = *(const u16x8*)(Kg + (size_t)(i * 16 + sr) * HD + sc8);
#pragma unroll
    for (int i = 0; i < 8; i++)
        Vreg[i] = *(const u16x8*)(Vg + (size_t)(i * 16 + sr) * SEQ + sc8);

    f32x4 acc[2][8];
#pragma unroll
    for (int qi = 0; qi < 2; qi++)
#pragma unroll
        for (int d = 0; d < 8; d++) acc[qi][d] = (f32x4){0.f, 0.f, 0.f, 0.f};
    float lp[2] = {0.f, 0.f};

    for (int kt = 0; kt < SEQ; kt += 128) {
        const int np = kt + 128;
        __syncthreads();                // prev PV reads of KV done
#pragma unroll
        for (int i = 0; i < 8; i++)     // stage K_i; refill Kreg = K_{i+1}
            *(u16x8*)&KV[(i * 16 + sr) * 136 + sc8] = Kreg[i];
        if (np < SEQ) {
#pragma unroll
            for (int i = 0; i < 8; i++)
                Kreg[i] = *(const u16x8*)(Kg + (size_t)(np + i * 16 + sr) * HD + sc8);
        }
        __syncthreads();

        // ---- scores transposed: sc[qi][j] = K(16 rows) x Q(16 rows)^T ----
        f32x4 sc[2][8];
#pragma unroll
        for (int qi = 0; qi < 2; qi++)
#pragma unroll
            for (int j = 0; j < 8; j++) sc[qi][j] = (f32x4){0.f, 0.f, 0.f, 0.f};
#pragma unroll
        for (int ks = 0; ks < 4; ks++) {
#pragma unroll
            for (int jh = 0; jh < 2; jh++) {
                bf16x8 kf[4];
#pragma unroll
                for (int j = 0; j < 4; j++)
                    kf[j] = *(const bf16x8*)&KV[((jh * 4 + j) * 16 + l15) * 136 + ks * 32 + quad * 8];
#pragma unroll
                for (int qi = 0; qi < 2; qi++)
#pragma unroll
                    for (int j = 0; j < 4; j++)
                        sc[qi][jh * 4 + j] = __builtin_amdgcn_mfma_f32_16x16x32_bf16(
                            kf[j], qf[qi][ks], sc[qi][jh * 4 + j], 0, 0, 0);
            }
        }

        // ---- p = exp(score); accumulate l; write P (8B contiguous) ----
#pragma unroll
        for (int qi = 0; qi < 2; qi++) {
            const int prow = (w * 32 + qi * 16 + l15) * 136 + quad * 4;
#pragma unroll
            for (int j = 0; j < 8; j++) {
                float p0 = __expf(sc[qi][j][0]);
                float p1 = __expf(sc[qi][j][1]);
                float p2 = __expf(sc[qi][j][2]);
                float p3 = __expf(sc[qi][j][3]);
                lp[qi] += (p0 + p1) + (p2 + p3);
                __hip_bfloat162 lo2 = __float22bfloat162_rn({p0, p1});
                __hip_bfloat162 hi2 = __float22bfloat162_rn({p2, p3});
                uint2 pk = make_uint2(*(u32*)&lo2, *(u32*)&hi2);
                *(uint2*)&Ps[prow + j * 16] = pk;
            }
        }
        __syncthreads();                // kf reads done + Ps visible
#pragma unroll
        for (int i = 0; i < 8; i++)     // stage V_i; refill Vreg = V_{i+1}
            *(u16x8*)&KV[(i * 16 + sr) * 136 + sc8] = Vreg[i];
        if (np < SEQ) {
#pragma unroll
            for (int i = 0; i < 8; i++)
                Vreg[i] = *(const u16x8*)(Vg + (size_t)(i * 16 + sr) * SEQ + np + sc8);
        }
        __syncthreads();

        // ---- PV transposed: acc[qi][db] = V^T(16 d-rows) x P^T ----
#pragma unroll
        for (int ks = 0; ks < 4; ks++) {
            bf16x8 pf[2];
#pragma unroll
            for (int qi = 0; qi < 2; qi++)
                pf[qi] = *(const bf16x8*)&Ps[(w * 32 + qi * 16 + l15) * 136 + ks * 32 + quad * 8];
#pragma unroll
            for (int db = 0; db < 8; db++) {
                bf16x8 vf = *(const bf16x8*)&KV[(db * 16 + l15) * 136 + ks * 32 + quad * 8];
#pragma unroll
                for (int qi = 0; qi < 2; qi++)
                    acc[qi][db] = __builtin_amdgcn_mfma_f32_16x16x32_bf16(vf, pf[qi], acc[qi][db], 0, 0, 0);
            }
        }
    }

    // ---- epilogue: l-reduce, normalize, re-layout via Ps, coalesced store ----
    float inv[2];
#pragma unroll
    for (int qi = 0; qi < 2; qi++) {
        float l = lp[qi];
        l += __shfl_xor(l, 16);
        l += __shfl_xor(l, 32);
        inv[qi] = 1.0f / l;
    }
    const size_t obase = ((size_t)bh * SEQ + ((size_t)qt << 7)) * HD;

    __syncthreads();                    // final PV pf reads of Ps done
    // hi pass
#pragma unroll
    for (int qi = 0; qi < 2; qi++)
#pragma unroll
        for (int db = 0; db < 8; db++) {
            ushort4 hh;
            ushort_t dum;
            split1(acc[qi][db][0] * inv[qi], hh.x, dum);
            split1(acc[qi][db][1] * inv[qi], hh.y, dum);
            split1(acc[qi][db][2] * inv[qi], hh.z, dum);
            split1(acc[qi][db][3] * inv[qi], hh.w, dum);
            *(ushort4*)&Ps[(w * 32 + qi * 16 + l15) * 136 + db * 16 + quad * 4] = hh;
        }
    __syncthreads();
#pragma unroll
    for (int t2 = 0; t2 < 8; t2++) {
        int c = t2 * 256 + tid;
        int row = c >> 4, col8 = (c & 15) << 3;
        *(u16x8*)&ch[obase + (size_t)row * HD + col8] = *(const u16x8*)&Ps[row * 136 + col8];
    }
    __syncthreads();
    // lo pass
#pragma unroll
    for (int qi = 0; qi < 2; qi++)
#pragma unroll
        for (int db = 0; db < 8; db++) {
            ushort4 ll;
            ushort_t dum;
            split1(acc[qi][db][0] * inv[qi], dum, ll.x);
            split1(acc[qi][db][1] * inv[qi], dum, ll.y);
            split1(acc[qi][db][2] * inv[qi], dum, ll.z);
            split1(acc[qi][db][3] * inv[qi], dum, ll.w);
            *(ushort4*)&Ps[(w * 32 + qi * 16 + l15) * 136 + db * 16 + quad * 4] = ll;
        }
    __syncthreads();
#pragma unroll
    for (int t2 = 0; t2 < 8; t2++) {
        int c = t2 * 256 + tid;
        int row = c >> 4, col8 = (c & 15) << 3;
        *(u16x8*)&cl[obase + (size_t)row * HD + col8] = *(const u16x8*)&Ps[row * 136 + col8];
    }
}

// ==================== launch =================================================
extern "C" void kernel_launch(void* const* d_in, const int* in_sizes, int n_in,
                              void* d_out, int out_size, void* d_ws, size_t ws_size,
                              hipStream_t stream) {
    const float* X  = (const float*)d_in[0];
    const float* Wq = (const float*)d_in[1];
    const float* bq = (const float*)d_in[2];
    const float* Wk = (const float*)d_in[3];
    const float* bk = (const float*)d_in[4];
    const float* Wv = (const float*)d_in[5];
    const float* bv = (const float*)d_in[6];
    const float* Wo = (const float*)d_in[7];
    const float* bo = (const float*)d_in[8];
    float* out = (float*)d_out;

    const size_t QS = (size_t)NB * NH * SEQ * HD;   // 8,388,608 elems
    const size_t WS = (size_t)HIDDEN * HIDDEN;      // 4,194,304 elems
    ushort_t* qb_ws = (ushort_t*)d_ws;              // bf16 blocked QKV outputs
    ushort_t* kb_ws = qb_ws + QS;
    ushort_t* vb_ws = kb_ws + QS;
    float* cost = (float*)(vb_ws + QS);
    float* sint = cost + (size_t)SEQ * 64;
    ushort_t* Xh = (ushort_t*)(sint + (size_t)SEQ * 64);  // -> Qb after QKV
    ushort_t* Wh0 = Xh + QS;
    ushort_t* Wh1 = Wh0 + WS;
    ushort_t* Wh2 = Wh1 + WS;
    ushort_t* Woh = Wh2 + WS;
    ushort_t* Wol = Woh + WS;
    ushort_t* Kb  = Wol + WS;
    ushort_t* Vtb = Kb + QS;
    ushort_t* ctxh = qb_ws;                         // ctx over dead qb/kb
    ushort_t* ctxl = kb_ws;

    k_rope_tables<<<(SEQ * 64) / 256, 256, 0, stream>>>(cost, sint);

    k_cvt_all<<<(XG + 4 * WG) / 256, 256, 0, stream>>>(
        (const float4*)X, (const float4*)Wq, (const float4*)Wk, (const float4*)Wv,
        (const float4*)Wo,
        (ushort4*)Xh, (ushort4*)Wh0, (ushort4*)Wh1, (ushort4*)Wh2,
        (ushort4*)Woh, (ushort4*)Wol);

    k_gemm_qkv8<<<384, 512, 0, stream>>>(Xh, Wh0, Wh1, Wh2, bq, bk, bv,
                                         qb_ws, kb_ws, vb_ws);

    ushort_t* Qbb = Xh;   // X bf16 dead after QKV GEMM
    k_rope_vpack<<<16384 + 2048, 256, 0, stream>>>(qb_ws, kb_ws, vb_ws, cost, sint,
                                                   Qbb, Kb, Vtb);

    k_flash_mfma<<<512, 256, 0, stream>>>(Qbb, Kb, Vtb, ctxh, ctxl);

    k_gemm_o2<<<dim3(256), 512, 0, stream>>>(ctxh, ctxl, Woh, Wol, bo, out);
}

// Round 8
// 469.700 us; speedup vs baseline: 1.0939x; 1.0681x over previous
//
#include <hip/hip_runtime.h>
#include <hip/hip_bf16.h>
#include <math.h>

#define HIDDEN 2048
#define NH 16
#define HD 128
#define NB 2
#define SEQ 2048
#define K_DIM 2048

typedef unsigned int u32;
typedef unsigned short ushort_t;
typedef __bf16 bf16x8 __attribute__((ext_vector_type(8)));
typedef float f32x4 __attribute__((ext_vector_type(4)));
typedef ushort_t u16x8 __attribute__((ext_vector_type(8)));

// ---------- fp32 -> (bf16 hi, bf16 lo) split, RNE both halves ----------
__device__ __forceinline__ void split1(float x, unsigned short& h, unsigned short& l) {
    u32 u = __float_as_uint(x);
    u32 hr = (u + 0x7FFFu + ((u >> 16) & 1u)) >> 16;
    h = (unsigned short)hr;
    float r = x - __uint_as_float(hr << 16);
    u32 u2 = __float_as_uint(r);
    l = (unsigned short)((u2 + 0x7FFFu + ((u2 >> 16) & 1u)) >> 16);
}

__device__ __forceinline__ ushort_t bf16r(float x) {
    u32 u = __float_as_uint(x);
    return (ushort_t)((u + 0x7FFFu + ((u >> 16) & 1u)) >> 16);
}

__device__ __forceinline__ float bf2f(ushort_t u) {
    return __uint_as_float(((u32)u) << 16);
}

__device__ __forceinline__ void gl_lds16(const void* g, void* l) {
    __builtin_amdgcn_global_load_lds(
        (const __attribute__((address_space(1))) u32*)g,
        (__attribute__((address_space(3))) u32*)l, 16, 0, 0);
}

// ==================== RoPE tables (double-precision trig) ====================
__global__ void k_rope_tables(float* __restrict__ ct, float* __restrict__ st) {
    int idx = blockIdx.x * 256 + threadIdx.x;   // exactly SEQ*64 threads
    int s = idx >> 6, d = idx & 63;
    double inv = pow(10000.0, -(double)d * (1.0 / 64.0));
    double ang = (double)s * inv;
    ct[idx] = (float)cos(ang);
    st[idx] = (float)sin(ang);
}

// ========== fused fp32->bf16: X,Wq,Wk,Wv (hi) + Wo (hi/lo split) =============
#define XG 2097152   // X float4 groups
#define WG 1048576   // W float4 groups
__global__ void k_cvt_all(const float4* __restrict__ X, const float4* __restrict__ W0,
                          const float4* __restrict__ W1, const float4* __restrict__ W2,
                          const float4* __restrict__ Wo,
                          ushort4* __restrict__ Xh, ushort4* __restrict__ H0,
                          ushort4* __restrict__ H1, ushort4* __restrict__ H2,
                          ushort4* __restrict__ WoH, ushort4* __restrict__ WoL) {
    int idx = blockIdx.x * 256 + threadIdx.x;   // XG + 4*WG threads
    if (idx < XG + 3 * WG) {
        const float4* src;
        ushort4* dst;
        int off;
        if (idx < XG) { src = X; dst = Xh; off = idx; }
        else {
            int t = idx - XG;
            int m = t >> 20;        // WG = 2^20
            off = t & (WG - 1);
            src = (m == 0) ? W0 : (m == 1) ? W1 : W2;
            dst = (m == 0) ? H0 : (m == 1) ? H1 : H2;
        }
        float4 x = src[off];
        ushort4 h;
        h.x = bf16r(x.x); h.y = bf16r(x.y); h.z = bf16r(x.z); h.w = bf16r(x.w);
        dst[off] = h;
    } else {
        int off = idx - XG - 3 * WG;
        float4 x = Wo[off];
        ushort4 h, l;
        split1(x.x, h.x, l.x);
        split1(x.y, h.y, l.y);
        split1(x.z, h.z, l.z);
        split1(x.w, h.w, l.w);
        WoH[off] = h;
        WoL[off] = l;
    }
}

// ==================== common waitcnt/barrier macros ==========================
#define BAR  __builtin_amdgcn_s_barrier()
#define VM6  asm volatile("s_waitcnt vmcnt(6)" ::: "memory")
#define VM4  asm volatile("s_waitcnt vmcnt(4)" ::: "memory")
#define VM0  asm volatile("s_waitcnt vmcnt(0)" ::: "memory")
#define PRIO1 __builtin_amdgcn_s_setprio(1)
#define PRIO0 __builtin_amdgcn_s_setprio(0)

// ==================== fused QKV: 256x256, BK=32, 4-slot rotation =============
// R5 schedule (verified): phase p = {STAGE(tile p+2 -> slot (p+2)&3); VM4;
// BAR_p; RD(tile p+1 -> other reg set); MFMA(tile p on current set)}.
// Invariant A (gate): VM4 pre-BAR -> at BAR_p every wave certified its
// tile-(p+1) loads complete. Invariant B: stage@p targets slot of tile p-2,
// reads drained by MFMA@p-1 before BAR_{p-1} < overwrite issue. S=4 >= L+2.
// Epilogue writes bf16 directly (halves write traffic vs fp32).
#define QSTAGE(slot, kt) do { \
    const ushort_t* gA_ = Xh + sgA + (size_t)(kt) * 32; \
    gl_lds16(gA_, &As[slot][(w * 32) * 32]); \
    gl_lds16(gA_ + 16 * 2048, &As[slot][(w * 32 + 16) * 32]); \
    const ushort_t* gB_ = Wsel + sgB + (size_t)(kt) * 32; \
    gl_lds16(gB_, &Bs[slot][(w * 32) * 32]); \
    gl_lds16(gB_ + 16 * 2048, &Bs[slot][(w * 32 + 16) * 32]); \
} while (0)

#define QRD(AD, BD, slot) do { \
    _Pragma("unroll") for (int mf = 0; mf < 8; mf++) \
        AD[mf] = *(const bf16x8*)&As[slot][arow + mf * 512 + ccq]; \
    _Pragma("unroll") for (int nf = 0; nf < 4; nf++) \
        BD[nf] = *(const bf16x8*)&Bs[slot][brow + nf * 512 + ccq]; \
} while (0)

#define QMFMA(AD, BD) do { PRIO1; \
    _Pragma("unroll") for (int mf = 0; mf < 8; mf++) \
    _Pragma("unroll") for (int nf = 0; nf < 4; nf++) \
        acc[mf][nf] = __builtin_amdgcn_mfma_f32_16x16x32_bf16( \
            AD[mf], BD[nf], acc[mf][nf], 0, 0, 0); \
    PRIO0; } while (0)

__global__ __launch_bounds__(512, 2)
void k_gemm_qkv8(const ushort_t* __restrict__ Xh,
                 const ushort_t* __restrict__ W0, const ushort_t* __restrict__ W1,
                 const ushort_t* __restrict__ W2,
                 const float* __restrict__ b0, const float* __restrict__ b1,
                 const float* __restrict__ b2,
                 ushort_t* __restrict__ o0, ushort_t* __restrict__ o1,
                 ushort_t* __restrict__ o2) {
    __shared__ ushort_t As[4][256 * 32];
    __shared__ ushort_t Bs[4][256 * 32];
    const int tid = threadIdx.x;
    const int lane = tid & 63;
    const int w = tid >> 6;        // wave 0..7
    const int wm = w >> 2;         // 0..1  (128 output rows each)
    const int wn = w & 3;          // 0..3  (64 output cols each)
    const int quad = lane >> 4;
    const int l15 = lane & 15;

    // bijective XCD swizzle (384 % 8 == 0)
    int bid = blockIdx.x;
    bid = (bid & 7) * 48 + (bid >> 3);
    const int bx = bid & 15;       // m-block
    const int by = bid >> 4;       // 0..23
    const int m0 = bx << 8;
    const int mat = by >> 3;
    const int n0 = (by & 7) << 8;
    const ushort_t* Wsel = (mat == 0) ? W0 : (mat == 1) ? W1 : W2;
    const float* bias = (mat == 0) ? b0 : (mat == 1) ? b1 : b2;
    ushort_t* out = (mat == 0) ? o0 : (mat == 1) ? o1 : o2;

    // staging: wave w covers rows [w*32, w*32+32); lane -> (row lrow4, slot
    // lane&3); global col slot pre-swizzled.
    const int lrow4 = lane >> 2;
    const int col8 = (((lane & 3) ^ ((lrow4 >> 1) & 3)) << 3);
    const size_t sgA = (size_t)(m0 + w * 32 + lrow4) * 2048 + col8;
    const size_t sgB = (size_t)(n0 + w * 32 + lrow4) * 2048 + col8;

    // fragment reads: row R wants global slot q -> LDS slot q^((R>>1)&3)
    const int arow = (wm * 128 + l15) * 32;
    const int brow = (wn * 64 + l15) * 32;
    const int ccq = ((quad ^ ((l15 >> 1) & 3)) << 3);

    f32x4 acc[8][4];
#pragma unroll
    for (int i = 0; i < 8; i++)
#pragma unroll
        for (int j = 0; j < 4; j++) acc[i][j] = (f32x4){0.f, 0.f, 0.f, 0.f};

    bf16x8 aA[8], bA[4], aB[8], bB[4];

    // prologue: tiles 0,1 staged; VM4 pre-BAR certifies tile0 for all waves
    QSTAGE(0, 0); QSTAGE(1, 1);
    VM4; BAR;
    QRD(aA, bA, 0);

    // phases 0..59 (15 iters x 4 phases; slots compile-time constants)
    for (int p = 0; p < 60; p += 4) {
        QSTAGE(2, p + 2); VM4; BAR; QRD(aB, bB, 1); QMFMA(aA, bA);   // tile p
        QSTAGE(3, p + 3); VM4; BAR; QRD(aA, bA, 2); QMFMA(aB, bB);   // tile p+1
        QSTAGE(0, p + 4); VM4; BAR; QRD(aB, bB, 3); QMFMA(aA, bA);   // tile p+2
        QSTAGE(1, p + 5); VM4; BAR; QRD(aA, bA, 0); QMFMA(aB, bB);   // tile p+3
    }
    // tail phases 60..63
    QSTAGE(2, 62); VM4; BAR; QRD(aB, bB, 1); QMFMA(aA, bA);          // tile 60
    QSTAGE(3, 63); VM4; BAR; QRD(aA, bA, 2); QMFMA(aB, bB);          // tile 61
    VM0; BAR;                QRD(aB, bB, 3); QMFMA(aA, bA);          // tile 62
    QMFMA(aB, bB);                                                   // tile 63

    // ---- epilogue: bias + bf16 store to blocked (B,NH,S,HD) ----
    float bcolv[4];
#pragma unroll
    for (int nf = 0; nf < 4; nf++) bcolv[nf] = bias[n0 + wn * 64 + nf * 16 + l15];

    const int mbase = m0 + wm * 128 + quad * 4;
#pragma unroll
    for (int mf = 0; mf < 8; mf++)
#pragma unroll
        for (int nf = 0; nf < 4; nf++) {
            const int n = n0 + wn * 64 + nf * 16 + l15;
            const int hh = n >> 7;
            const int d = n & 127;
#pragma unroll
            for (int r = 0; r < 4; r++) {
                const int m = mbase + mf * 16 + r;
                const int bb = m >> 11;
                const int s = m & (SEQ - 1);
                out[((size_t)(bb * NH + hh) * SEQ + s) * HD + d] =
                    bf16r(acc[mf][nf][r] + bcolv[nf]);
            }
        }
}

// ==================== O-projection: 256x128, BK=32, 3-slot rotation ==========
// R5 schedule (verified): phase q = {VM0; BAR_q; STAGE(tile q+2 ->
// slot (q+2)%3); RD(tile q+1 <- slot (q+1)%3); MFMA(tile q)}.
// Invariant A: tile q+1 staged @ q-1 post-BAR_{q-1}; VM0@q pre-BAR drains
// per-wave -> certified globally at BAR_q (loads ~1 MFMA phase old).
// Invariant B: slot (q+2)%3 holds tile q-1, reads drained by MFMA@q-1 in
// [BAR_{q-1}, BAR_q]; overwrite DMA issues post-BAR_q.
#define OSTAGE(slot, kt) do { \
    const size_t koA = (size_t)((kt) >> 2) * ((size_t)SEQ * HD) + (size_t)((kt) & 3) * 32; \
    const size_t koB = (size_t)(kt) * 32; \
    gl_lds16(Ah + sgA0 + koA, &Ah_s[slot][(w * 32) * 32]); \
    gl_lds16(Ah + sgA0 + 16 * HD + koA, &Ah_s[slot][(w * 32 + 16) * 32]); \
    gl_lds16(Al + sgA0 + koA, &Al_s[slot][(w * 32) * 32]); \
    gl_lds16(Al + sgA0 + 16 * HD + koA, &Al_s[slot][(w * 32 + 16) * 32]); \
    gl_lds16(Bh + sgB0 + koB, &Bh_s[slot][(w * 16) * 32]); \
    gl_lds16(Bl + sgB0 + koB, &Bl_s[slot][(w * 16) * 32]); \
} while (0)

#define ORD(AH, AL, BH, BL, slot) do { \
    _Pragma("unroll") for (int f = 0; f < 4; f++) { \
        AH[f] = *(const bf16x8*)&Ah_s[slot][aro + f * 512 + cco]; \
        AL[f] = *(const bf16x8*)&Al_s[slot][aro + f * 512 + cco]; \
        BH[f] = *(const bf16x8*)&Bh_s[slot][bro + f * 512 + cco]; \
        BL[f] = *(const bf16x8*)&Bl_s[slot][bro + f * 512 + cco]; \
    } \
} while (0)

#define OMFMA(AH, AL, BH, BL) do { PRIO1; \
    _Pragma("unroll") for (int mf = 0; mf < 4; mf++) \
    _Pragma("unroll") for (int nf = 0; nf < 4; nf++) { \
        acc[mf][nf] = __builtin_amdgcn_mfma_f32_16x16x32_bf16( \
            AH[mf], BH[nf], acc[mf][nf], 0, 0, 0); \
        acc[mf][nf] = __builtin_amdgcn_mfma_f32_16x16x32_bf16( \
            AH[mf], BL[nf], acc[mf][nf], 0, 0, 0); \
        acc[mf][nf] = __builtin_amdgcn_mfma_f32_16x16x32_bf16( \
            AL[mf], BH[nf], acc[mf][nf], 0, 0, 0); \
    } PRIO0; } while (0)

__global__ __launch_bounds__(512, 2)
void k_gemm_o2(const ushort_t* __restrict__ Ah, const ushort_t* __restrict__ Al,
               const ushort_t* __restrict__ Bh, const ushort_t* __restrict__ Bl,
               const float* __restrict__ bias, float* __restrict__ out) {
    __shared__ ushort_t Ah_s[3][256 * 32];
    __shared__ ushort_t Al_s[3][256 * 32];
    __shared__ ushort_t Bh_s[3][128 * 32];
    __shared__ ushort_t Bl_s[3][128 * 32];
    const int tid = threadIdx.x;
    const int lane = tid & 63;
    const int w = tid >> 6;        // wave 0..7
    const int wm = w >> 1;         // 0..3 (64 output rows each)
    const int wn = w & 1;          // 0..1 (64 output cols each)
    const int quad = lane >> 4;
    const int l15 = lane & 15;

    // bijective XCD swizzle (256 % 8 == 0)
    int bid = blockIdx.x;
    bid = (bid & 7) * 32 + (bid >> 3);
    const int bx = bid & 15;       // m-block (0..15)
    const int by = bid >> 4;       // n-block (0..15)
    const int m0 = bx << 8;        // 256 rows
    const int n0 = by << 7;        // 128 cols

    // staging addressing (pre-swizzled global col slot, (r>>1)&3 XOR)
    const int lrow4 = lane >> 2;
    const int col8 = (((lane & 3) ^ ((lrow4 >> 1) & 3)) << 3);
    const size_t sgA0 = ((size_t)(m0 >> 11) * NH * SEQ + (size_t)((m0 & (SEQ - 1)) + w * 32 + lrow4)) * HD + col8;
    const size_t sgB0 = (size_t)(n0 + w * 16 + lrow4) * K_DIM + col8;

    // fragment reads
    const int aro = (wm * 64 + l15) * 32;
    const int bro = (wn * 64 + l15) * 32;
    const int cco = ((quad ^ ((l15 >> 1) & 3)) << 3);

    f32x4 acc[4][4];
#pragma unroll
    for (int i = 0; i < 4; i++)
#pragma unroll
        for (int j = 0; j < 4; j++) acc[i][j] = (f32x4){0.f, 0.f, 0.f, 0.f};

    bf16x8 ahA[4], alA[4], bhA[4], blA[4];
    bf16x8 ahB[4], alB[4], bhB[4], blB[4];

    // prologue: tiles 0,1 staged; VM6 pre-BAR certifies tile0 for all waves
    OSTAGE(0, 0);
    OSTAGE(1, 1);
    VM6; BAR;
    ORD(ahA, alA, bhA, blA, 0);

    // phases 0..59 (10 iters x 6 phases; slot/set pattern period 6)
    for (int it = 0; it < 10; ++it) {
        const int q = 6 * it;
        VM0; BAR; OSTAGE(2, q + 2); ORD(ahB, alB, bhB, blB, 1); OMFMA(ahA, alA, bhA, blA);  // tile q
        VM0; BAR; OSTAGE(0, q + 3); ORD(ahA, alA, bhA, blA, 2); OMFMA(ahB, alB, bhB, blB);  // q+1
        VM0; BAR; OSTAGE(1, q + 4); ORD(ahB, alB, bhB, blB, 0); OMFMA(ahA, alA, bhA, blA);  // q+2
        VM0; BAR; OSTAGE(2, q + 5); ORD(ahA, alA, bhA, blA, 1); OMFMA(ahB, alB, bhB, blB);  // q+3
        VM0; BAR; OSTAGE(0, q + 6); ORD(ahB, alB, bhB, blB, 2); OMFMA(ahA, alA, bhA, blA);  // q+4
        VM0; BAR; OSTAGE(1, q + 7); ORD(ahA, alA, bhA, blA, 0); OMFMA(ahB, alB, bhB, blB);  // q+5
    }
    // tail phases 60..63
    VM0; BAR; OSTAGE(2, 62); ORD(ahB, alB, bhB, blB, 1); OMFMA(ahA, alA, bhA, blA);  // tile 60
    VM0; BAR; OSTAGE(0, 63); ORD(ahA, alA, bhA, blA, 2); OMFMA(ahB, alB, bhB, blB);  // tile 61
    VM0; BAR;                ORD(ahB, alB, bhB, blB, 0); OMFMA(ahA, alA, bhA, blA);  // tile 62
    OMFMA(ahB, alB, bhB, blB);                                                        // tile 63

    // ---- epilogue: bias + coalesced fp32 store ----
    float bcolv[4];
#pragma unroll
    for (int nf = 0; nf < 4; nf++) bcolv[nf] = bias[n0 + wn * 64 + nf * 16 + l15];

    const int mb = m0 + wm * 64 + quad * 4;
    const int nb = n0 + wn * 64 + l15;
#pragma unroll
    for (int fm = 0; fm < 4; fm++)
#pragma unroll
        for (int fn = 0; fn < 4; fn++)
#pragma unroll
            for (int r = 0; r < 4; r++)
                out[(size_t)(mb + fm * 16 + r) * HIDDEN + nb + fn * 16] =
                    acc[fm][fn][r] + bcolv[fn];
}

// ========== fused RoPE-pack (bf16 in) + V transpose-pack (bf16 in) ===========
// blocks [0, 16384): RoPE on qb/kb (blocked bf16) -> Qb (scaled) / Kb
// blocks [16384, 18432): V transpose (B,H,S,D) bf16 -> (B,H,D,S) bf16
__global__ __launch_bounds__(256)
void k_rope_vpack(const ushort_t* __restrict__ qb, const ushort_t* __restrict__ kb,
                  const ushort_t* __restrict__ vb,
                  const float* __restrict__ ct, const float* __restrict__ st,
                  ushort_t* __restrict__ Qb, ushort_t* __restrict__ Kb,
                  ushort_t* __restrict__ vt) {
    __shared__ float t[64][65];
    const int tid = threadIdx.x;
    const int blk = blockIdx.x;
    if (blk < 16384) {
        // ---- RoPE path ----
        int idx = blk * 256 + tid;          // NB*NH*SEQ*64 threads
        int d = idx & 63;
        int s = (idx >> 6) & (SEQ - 1);
        int bh = idx >> 17;                 // 0..31
        size_t base = ((size_t)bh * SEQ + s) * HD;
        float c = ct[(s << 6) + d], sn = st[(s << 6) + d];
        const float scq = 0.08838834764831845f;
        float q0 = bf2f(qb[base + d]), q1 = bf2f(qb[base + d + 64]);
        Qb[base + d]      = bf16r((q0 * c - q1 * sn) * scq);
        Qb[base + d + 64] = bf16r((q1 * c + q0 * sn) * scq);
        float k0 = bf2f(kb[base + d]), k1 = bf2f(kb[base + d + 64]);
        Kb[base + d]      = bf16r(k0 * c - k1 * sn);
        Kb[base + d + 64] = bf16r(k1 * c + k0 * sn);
    } else {
        // ---- V transpose path ----
        int b = blk - 16384;                // 2048 blocks: (32 s, 2 d, 32 bh)
        const int s0 = (b & 31) << 6;
        const int d0 = ((b >> 5) & 1) << 6;
        const int bh = b >> 6;
        const ushort_t* src = vb + ((size_t)bh * SEQ + s0) * HD + d0;
        const int rr = tid >> 4;
        const int cc = (tid & 15) << 2;
#pragma unroll
        for (int i = 0; i < 4; i++) {
            ushort4 x = *(const ushort4*)(src + (size_t)(i * 16 + rr) * HD + cc);
            t[i * 16 + rr][cc]     = bf2f(x.x);
            t[i * 16 + rr][cc + 1] = bf2f(x.y);
            t[i * 16 + rr][cc + 2] = bf2f(x.z);
            t[i * 16 + rr][cc + 3] = bf2f(x.w);
        }
        __syncthreads();
        const int dr = tid >> 2;
        const int sc_ = (tid & 3) << 4;
        ushort_t* dst = vt + ((size_t)bh * HD + d0 + dr) * SEQ + s0 + sc_;
        u16x8 o0, o1;
#pragma unroll
        for (int u = 0; u < 8; u++) o0[u] = bf16r(t[sc_ + u][dr]);
#pragma unroll
        for (int u = 0; u < 8; u++) o1[u] = bf16r(t[sc_ + 8 + u][dr]);
        *(u16x8*)dst = o0;
        *(u16x8*)(dst + 8) = o1;
    }
}

// ==================== MFMA flash attention v5 ================================
// R8: kv-tile 64, SEPARATE K/V/Ps buffers, 2 barriers per tile.
// Key insight: Ps is WAVE-PRIVATE (wave w writes+reads only rows w*32..+31),
// so no barrier is needed between P-write and pf-read (lgkm auto-ordering).
// The old 4-barrier lockstep (stage-K | QK | stage-V | PV) collapses to:
//   {sync; stage K+V; refill regs; sync; QK^T -> exp -> P -> PV}
// giving one long compute region where de-phased waves co-utilize the MFMA,
// VALU (exp), and LDS pipes (m114 mechanism).
// Hazards: stage@t overwrites Ks/Vs whose last reads (kf@t-1, vf@t-1) are
// complete before sync#1 (register deps on consuming MFMAs); Ps rows never
// cross waves; epilogue aliases SH only after the final sync.
// LDS: Ks[64][136]=17KB + Vs[128][72]=18KB + Ps[128][72]=18KB = 53KB
// -> 2 blocks/CU (unchanged; occupancy is grid-capped at 8 waves/CU anyway).
__global__ __launch_bounds__(256, 2)
void k_flash_mfma(const ushort_t* __restrict__ Qb, const ushort_t* __restrict__ Kb,
                  const ushort_t* __restrict__ Vt,
                  ushort_t* __restrict__ ch, ushort_t* __restrict__ cl) {
    __shared__ ushort_t SH[27136];      // Ks @0 (8704) | Vs @8704 (9216) | Ps @17920 (9216)
    ushort_t* Ks = SH;
    ushort_t* Vs = SH + 8704;
    ushort_t* Ps = SH + 17920;
    const int tid = threadIdx.x;
    const int lane = tid & 63;
    const int w = tid >> 6;
    const int quad = lane >> 4;
    const int l15 = lane & 15;
    const int bi = blockIdx.x;
    const int bh = bi & 31;              // XCD swizzle: bh%8 == XCD id
    const int qt = bi >> 5;              // 0..15 (128 q rows each)
    const ushort_t* Qg = Qb + ((size_t)bh * SEQ + ((size_t)qt << 7)) * HD;
    const ushort_t* Kg = Kb + (size_t)bh * SEQ * HD;
    const ushort_t* Vg = Vt + (size_t)bh * HD * SEQ;

    // persistent Q fragments (B-operand): rows w*32+qi*16+l15, k = ks*32+quad*8
    bf16x8 qf[2][4];
#pragma unroll
    for (int qi = 0; qi < 2; qi++)
#pragma unroll
        for (int ks = 0; ks < 4; ks++)
            qf[qi][ks] = *(const bf16x8*)(Qg + (size_t)(w * 32 + qi * 16 + l15) * HD + ks * 32 + quad * 8);

    const int sr = tid >> 4;            // K staging row 0..15
    const int sc8 = (tid & 15) << 3;    // K staging col (16B)
    const int vr = tid >> 3;            // V staging row 0..31
    const int vc8 = (tid & 7) << 3;     // V staging col (16B)

    // prefetch tile 0: K rows [0,64), V^T cols [0,64)
    u16x8 Kreg[4], Vreg[4];
#pragma unroll
    for (int i = 0; i < 4; i++)
        Kreg[i] = *(const u16x8*)(Kg + (size_t)(i * 16 + sr) * HD + sc8);
#pragma unroll
    for (int i = 0; i < 4; i++)
        Vreg[i] = *(const u16x8*)(Vg + (size_t)(i * 32 + vr) * SEQ + vc8);

    f32x4 acc[2][8];
#pragma unroll
    for (int qi = 0; qi < 2; qi++)
#pragma unroll
        for (int d = 0; d < 8; d++) acc[qi][d] = (f32x4){0.f, 0.f, 0.f, 0.f};
    float lp[2] = {0.f, 0.f};

    for (int kt = 0; kt < SEQ; kt += 64) {
        const int np = kt + 64;
        __syncthreads();                // prev tile's kf/vf/pf reads done
#pragma unroll
        for (int i = 0; i < 4; i++)     // stage K tile
            *(u16x8*)&Ks[(i * 16 + sr) * 136 + sc8] = Kreg[i];
#pragma unroll
        for (int i = 0; i < 4; i++)     // stage V tile
            *(u16x8*)&Vs[(i * 32 + vr) * 72 + vc8] = Vreg[i];
        if (np < SEQ) {
#pragma unroll
            for (int i = 0; i < 4; i++)
                Kreg[i] = *(const u16x8*)(Kg + (size_t)(np + i * 16 + sr) * HD + sc8);
#pragma unroll
            for (int i = 0; i < 4; i++)
                Vreg[i] = *(const u16x8*)(Vg + (size_t)(i * 32 + vr) * SEQ + np + vc8);
        }
        __syncthreads();                // staging visible block-wide

        // ---- QK^T: sc[qi][j] = K(16 rows) x Q(16 rows)^T ----
        f32x4 sc[2][4];
#pragma unroll
        for (int qi = 0; qi < 2; qi++)
#pragma unroll
            for (int j = 0; j < 4; j++) sc[qi][j] = (f32x4){0.f, 0.f, 0.f, 0.f};
#pragma unroll
        for (int ks = 0; ks < 4; ks++) {
            bf16x8 kf[4];
#pragma unroll
            for (int j = 0; j < 4; j++)
                kf[j] = *(const bf16x8*)&Ks[(j * 16 + l15) * 136 + ks * 32 + quad * 8];
#pragma unroll
            for (int qi = 0; qi < 2; qi++)
#pragma unroll
                for (int j = 0; j < 4; j++)
                    sc[qi][j] = __builtin_amdgcn_mfma_f32_16x16x32_bf16(
                        kf[j], qf[qi][ks], sc[qi][j], 0, 0, 0);
        }

        // ---- p = exp(score); accumulate l; write P (wave-private rows) ----
#pragma unroll
        for (int qi = 0; qi < 2; qi++) {
            const int prow = (w * 32 + qi * 16 + l15) * 72 + quad * 4;
#pragma unroll
            for (int j = 0; j < 4; j++) {
                float p0 = __expf(sc[qi][j][0]);
                float p1 = __expf(sc[qi][j][1]);
                float p2 = __expf(sc[qi][j][2]);
                float p3 = __expf(sc[qi][j][3]);
                lp[qi] += (p0 + p1) + (p2 + p3);
                __hip_bfloat162 lo2 = __float22bfloat162_rn({p0, p1});
                __hip_bfloat162 hi2 = __float22bfloat162_rn({p2, p3});
                uint2 pk = make_uint2(*(u32*)&lo2, *(u32*)&hi2);
                *(uint2*)&Ps[prow + j * 16] = pk;
            }
        }

        // ---- PV: acc[qi][db] += V^T(16 d-rows) x P^T (no barrier: Ps rows
        //      are own-wave; Vs staged this tile) ----
#pragma unroll
        for (int ks = 0; ks < 2; ks++) {
            bf16x8 pf[2];
#pragma unroll
            for (int qi = 0; qi < 2; qi++)
                pf[qi] = *(const bf16x8*)&Ps[(w * 32 + qi * 16 + l15) * 72 + ks * 32 + quad * 8];
#pragma unroll
            for (int db = 0; db < 8; db++) {
                bf16x8 vf = *(const bf16x8*)&Vs[(db * 16 + l15) * 72 + ks * 32 + quad * 8];
#pragma unroll
                for (int qi = 0; qi < 2; qi++)
                    acc[qi][db] = __builtin_amdgcn_mfma_f32_16x16x32_bf16(vf, pf[qi], acc[qi][db], 0, 0, 0);
            }
        }
    }

    // ---- epilogue: l-reduce, normalize, re-layout via SH, coalesced store ----
    float inv[2];
#pragma unroll
    for (int qi = 0; qi < 2; qi++) {
        float l = lp[qi];
        l += __shfl_xor(l, 16);
        l += __shfl_xor(l, 32);
        inv[qi] = 1.0f / l;
    }
    const size_t obase = ((size_t)bh * SEQ + ((size_t)qt << 7)) * HD;

    __syncthreads();                    // final PV reads of Vs/Ps done
    // hi pass (SH reused as [128][136] scratch)
#pragma unroll
    for (int qi = 0; qi < 2; qi++)
#pragma unroll
        for (int db = 0; db < 8; db++) {
            ushort4 hh;
            ushort_t dum;
            split1(acc[qi][db][0] * inv[qi], hh.x, dum);
            split1(acc[qi][db][1] * inv[qi], hh.y, dum);
            split1(acc[qi][db][2] * inv[qi], hh.z, dum);
            split1(acc[qi][db][3] * inv[qi], hh.w, dum);
            *(ushort4*)&SH[(w * 32 + qi * 16 + l15) * 136 + db * 16 + quad * 4] = hh;
        }
    __syncthreads();
#pragma unroll
    for (int t2 = 0; t2 < 8; t2++) {
        int c = t2 * 256 + tid;
        int row = c >> 4, col8 = (c & 15) << 3;
        *(u16x8*)&ch[obase + (size_t)row * HD + col8] = *(const u16x8*)&SH[row * 136 + col8];
    }
    __syncthreads();
    // lo pass
#pragma unroll
    for (int qi = 0; qi < 2; qi++)
#pragma unroll
        for (int db = 0; db < 8; db++) {
            ushort4 ll;
            ushort_t dum;
            split1(acc[qi][db][0] * inv[qi], dum, ll.x);
            split1(acc[qi][db][1] * inv[qi], dum, ll.y);
            split1(acc[qi][db][2] * inv[qi], dum, ll.z);
            split1(acc[qi][db][3] * inv[qi], dum, ll.w);
            *(ushort4*)&SH[(w * 32 + qi * 16 + l15) * 136 + db * 16 + quad * 4] = ll;
        }
    __syncthreads();
#pragma unroll
    for (int t2 = 0; t2 < 8; t2++) {
        int c = t2 * 256 + tid;
        int row = c >> 4, col8 = (c & 15) << 3;
        *(u16x8*)&cl[obase + (size_t)row * HD + col8] = *(const u16x8*)&SH[row * 136 + col8];
    }
}

// ==================== launch =================================================
extern "C" void kernel_launch(void* const* d_in, const int* in_sizes, int n_in,
                              void* d_out, int out_size, void* d_ws, size_t ws_size,
                              hipStream_t stream) {
    const float* X  = (const float*)d_in[0];
    const float* Wq = (const float*)d_in[1];
    const float* bq = (const float*)d_in[2];
    const float* Wk = (const float*)d_in[3];
    const float* bk = (const float*)d_in[4];
    const float* Wv = (const float*)d_in[5];
    const float* bv = (const float*)d_in[6];
    const float* Wo = (const float*)d_in[7];
    const float* bo = (const float*)d_in[8];
    float* out = (float*)d_out;

    const size_t QS = (size_t)NB * NH * SEQ * HD;   // 8,388,608 elems
    const size_t WS = (size_t)HIDDEN * HIDDEN;      // 4,194,304 elems
    ushort_t* qb_ws = (ushort_t*)d_ws;              // bf16 blocked QKV outputs
    ushort_t* kb_ws = qb_ws + QS;
    ushort_t* vb_ws = kb_ws + QS;
    float* cost = (float*)(vb_ws + QS);
    float* sint = cost + (size_t)SEQ * 64;
    ushort_t* Xh = (ushort_t*)(sint + (size_t)SEQ * 64);  // -> Qb after QKV
    ushort_t* Wh0 = Xh + QS;
    ushort_t* Wh1 = Wh0 + WS;
    ushort_t* Wh2 = Wh1 + WS;
    ushort_t* Woh = Wh2 + WS;
    ushort_t* Wol = Woh + WS;
    ushort_t* Kb  = Wol + WS;
    ushort_t* Vtb = Kb + QS;
    ushort_t* ctxh = qb_ws;                         // ctx over dead qb/kb
    ushort_t* ctxl = kb_ws;

    k_rope_tables<<<(SEQ * 64) / 256, 256, 0, stream>>>(cost, sint);

    k_cvt_all<<<(XG + 4 * WG) / 256, 256, 0, stream>>>(
        (const float4*)X, (const float4*)Wq, (const float4*)Wk, (const float4*)Wv,
        (const float4*)Wo,
        (ushort4*)Xh, (ushort4*)Wh0, (ushort4*)Wh1, (ushort4*)Wh2,
        (ushort4*)Woh, (ushort4*)Wol);

    k_gemm_qkv8<<<384, 512, 0, stream>>>(Xh, Wh0, Wh1, Wh2, bq, bk, bv,
                                         qb_ws, kb_ws, vb_ws);

    ushort_t* Qbb = Xh;   // X bf16 dead after QKV GEMM
    k_rope_vpack<<<16384 + 2048, 256, 0, stream>>>(qb_ws, kb_ws, vb_ws, cost, sint,
                                                   Qbb, Kb, Vtb);

    k_flash_mfma<<<512, 256, 0, stream>>>(Qbb, Kb, Vtb, ctxh, ctxl);

    k_gemm_o2<<<dim3(256), 512, 0, stream>>>(ctxh, ctxl, Woh, Wol, bo, out);
}

// Round 9
// 446.694 us; speedup vs baseline: 1.1502x; 1.0515x over previous
//
#include <hip/hip_runtime.h>
#include <hip/hip_bf16.h>
#include <math.h>

#define HIDDEN 2048
#define NH 16
#define HD 128
#define NB 2
#define SEQ 2048
#define K_DIM 2048

typedef unsigned int u32;
typedef unsigned short ushort_t;
typedef __bf16 bf16x8 __attribute__((ext_vector_type(8)));
typedef float f32x4 __attribute__((ext_vector_type(4)));
typedef ushort_t u16x8 __attribute__((ext_vector_type(8)));

// ---------- fp32 -> (bf16 hi, bf16 lo) split, RNE both halves ----------
__device__ __forceinline__ void split1(float x, unsigned short& h, unsigned short& l) {
    u32 u = __float_as_uint(x);
    u32 hr = (u + 0x7FFFu + ((u >> 16) & 1u)) >> 16;
    h = (unsigned short)hr;
    float r = x - __uint_as_float(hr << 16);
    u32 u2 = __float_as_uint(r);
    l = (unsigned short)((u2 + 0x7FFFu + ((u2 >> 16) & 1u)) >> 16);
}

__device__ __forceinline__ ushort_t bf16r(float x) {
    u32 u = __float_as_uint(x);
    return (ushort_t)((u + 0x7FFFu + ((u >> 16) & 1u)) >> 16);
}

__device__ __forceinline__ float bf2f(ushort_t u) {
    return __uint_as_float(((u32)u) << 16);
}

__device__ __forceinline__ void gl_lds16(const void* g, void* l) {
    __builtin_amdgcn_global_load_lds(
        (const __attribute__((address_space(1))) u32*)g,
        (__attribute__((address_space(3))) u32*)l, 16, 0, 0);
}

// ====== fused: RoPE tables (blocks 0..511) + fp32->bf16 conversions ==========
#define XG 2097152   // X float4 groups
#define WG 1048576   // W float4 groups
#define TBLK 512     // table blocks (SEQ*64 threads)
__global__ void k_cvt_all(const float4* __restrict__ X, const float4* __restrict__ W0,
                          const float4* __restrict__ W1, const float4* __restrict__ W2,
                          const float4* __restrict__ Wo,
                          ushort4* __restrict__ Xh, ushort4* __restrict__ H0,
                          ushort4* __restrict__ H1, ushort4* __restrict__ H2,
                          ushort4* __restrict__ WoH, ushort4* __restrict__ WoL,
                          float* __restrict__ ct, float* __restrict__ st) {
    const int blk = blockIdx.x;
    if (blk < TBLK) {
        int idx = blk * 256 + threadIdx.x;    // SEQ*64 threads
        int s = idx >> 6, d = idx & 63;
        double inv = pow(10000.0, -(double)d * (1.0 / 64.0));
        double ang = (double)s * inv;
        ct[idx] = (float)cos(ang);
        st[idx] = (float)sin(ang);
        return;
    }
    int idx = (blk - TBLK) * 256 + threadIdx.x;   // XG + 4*WG threads
    if (idx < XG + 3 * WG) {
        const float4* src;
        ushort4* dst;
        int off;
        if (idx < XG) { src = X; dst = Xh; off = idx; }
        else {
            int t = idx - XG;
            int m = t >> 20;        // WG = 2^20
            off = t & (WG - 1);
            src = (m == 0) ? W0 : (m == 1) ? W1 : W2;
            dst = (m == 0) ? H0 : (m == 1) ? H1 : H2;
        }
        float4 x = src[off];
        ushort4 h;
        h.x = bf16r(x.x); h.y = bf16r(x.y); h.z = bf16r(x.z); h.w = bf16r(x.w);
        dst[off] = h;
    } else {
        int off = idx - XG - 3 * WG;
        float4 x = Wo[off];
        ushort4 h, l;
        split1(x.x, h.x, l.x);
        split1(x.y, h.y, l.y);
        split1(x.z, h.z, l.z);
        split1(x.w, h.w, l.w);
        WoH[off] = h;
        WoL[off] = l;
    }
}

// ==================== common waitcnt/barrier macros ==========================
#define BAR  __builtin_amdgcn_s_barrier()
#define VM6  asm volatile("s_waitcnt vmcnt(6)" ::: "memory")
#define VM4  asm volatile("s_waitcnt vmcnt(4)" ::: "memory")
#define VM0  asm volatile("s_waitcnt vmcnt(0)" ::: "memory")
#define PRIO1 __builtin_amdgcn_s_setprio(1)
#define PRIO0 __builtin_amdgcn_s_setprio(0)

// ==================== fused QKV: 256x256, BK=32, 4-slot rotation =============
// R5 schedule (verified): phase p = {STAGE(tile p+2 -> slot (p+2)&3); VM4;
// BAR_p; RD(tile p+1 -> other reg set); MFMA(tile p on current set)}.
// Invariant A (gate): VM4 pre-BAR -> at BAR_p every wave certified its
// tile-(p+1) loads complete. Invariant B: stage@p targets slot of tile p-2,
// reads drained by MFMA@p-1 before BAR_{p-1} < overwrite issue. S=4 >= L+2.
// Epilogue writes bf16 directly (halves write traffic vs fp32).
#define QSTAGE(slot, kt) do { \
    const ushort_t* gA_ = Xh + sgA + (size_t)(kt) * 32; \
    gl_lds16(gA_, &As[slot][(w * 32) * 32]); \
    gl_lds16(gA_ + 16 * 2048, &As[slot][(w * 32 + 16) * 32]); \
    const ushort_t* gB_ = Wsel + sgB + (size_t)(kt) * 32; \
    gl_lds16(gB_, &Bs[slot][(w * 32) * 32]); \
    gl_lds16(gB_ + 16 * 2048, &Bs[slot][(w * 32 + 16) * 32]); \
} while (0)

#define QRD(AD, BD, slot) do { \
    _Pragma("unroll") for (int mf = 0; mf < 8; mf++) \
        AD[mf] = *(const bf16x8*)&As[slot][arow + mf * 512 + ccq]; \
    _Pragma("unroll") for (int nf = 0; nf < 4; nf++) \
        BD[nf] = *(const bf16x8*)&Bs[slot][brow + nf * 512 + ccq]; \
} while (0)

#define QMFMA(AD, BD) do { PRIO1; \
    _Pragma("unroll") for (int mf = 0; mf < 8; mf++) \
    _Pragma("unroll") for (int nf = 0; nf < 4; nf++) \
        acc[mf][nf] = __builtin_amdgcn_mfma_f32_16x16x32_bf16( \
            AD[mf], BD[nf], acc[mf][nf], 0, 0, 0); \
    PRIO0; } while (0)

__global__ __launch_bounds__(512, 2)
void k_gemm_qkv8(const ushort_t* __restrict__ Xh,
                 const ushort_t* __restrict__ W0, const ushort_t* __restrict__ W1,
                 const ushort_t* __restrict__ W2,
                 const float* __restrict__ b0, const float* __restrict__ b1,
                 const float* __restrict__ b2,
                 ushort_t* __restrict__ o0, ushort_t* __restrict__ o1,
                 ushort_t* __restrict__ o2) {
    __shared__ ushort_t As[4][256 * 32];
    __shared__ ushort_t Bs[4][256 * 32];
    const int tid = threadIdx.x;
    const int lane = tid & 63;
    const int w = tid >> 6;        // wave 0..7
    const int wm = w >> 2;         // 0..1  (128 output rows each)
    const int wn = w & 3;          // 0..3  (64 output cols each)
    const int quad = lane >> 4;
    const int l15 = lane & 15;

    // bijective XCD swizzle (384 % 8 == 0)
    int bid = blockIdx.x;
    bid = (bid & 7) * 48 + (bid >> 3);
    const int bx = bid & 15;       // m-block
    const int by = bid >> 4;       // 0..23
    const int m0 = bx << 8;
    const int mat = by >> 3;
    const int n0 = (by & 7) << 8;
    const ushort_t* Wsel = (mat == 0) ? W0 : (mat == 1) ? W1 : W2;
    const float* bias = (mat == 0) ? b0 : (mat == 1) ? b1 : b2;
    ushort_t* out = (mat == 0) ? o0 : (mat == 1) ? o1 : o2;

    // staging: wave w covers rows [w*32, w*32+32); lane -> (row lrow4, slot
    // lane&3); global col slot pre-swizzled.
    const int lrow4 = lane >> 2;
    const int col8 = (((lane & 3) ^ ((lrow4 >> 1) & 3)) << 3);
    const size_t sgA = (size_t)(m0 + w * 32 + lrow4) * 2048 + col8;
    const size_t sgB = (size_t)(n0 + w * 32 + lrow4) * 2048 + col8;

    // fragment reads: row R wants global slot q -> LDS slot q^((R>>1)&3)
    const int arow = (wm * 128 + l15) * 32;
    const int brow = (wn * 64 + l15) * 32;
    const int ccq = ((quad ^ ((l15 >> 1) & 3)) << 3);

    f32x4 acc[8][4];
#pragma unroll
    for (int i = 0; i < 8; i++)
#pragma unroll
        for (int j = 0; j < 4; j++) acc[i][j] = (f32x4){0.f, 0.f, 0.f, 0.f};

    bf16x8 aA[8], bA[4], aB[8], bB[4];

    // prologue: tiles 0,1 staged; VM4 pre-BAR certifies tile0 for all waves
    QSTAGE(0, 0); QSTAGE(1, 1);
    VM4; BAR;
    QRD(aA, bA, 0);

    // phases 0..59 (15 iters x 4 phases; slots compile-time constants)
    for (int p = 0; p < 60; p += 4) {
        QSTAGE(2, p + 2); VM4; BAR; QRD(aB, bB, 1); QMFMA(aA, bA);   // tile p
        QSTAGE(3, p + 3); VM4; BAR; QRD(aA, bA, 2); QMFMA(aB, bB);   // tile p+1
        QSTAGE(0, p + 4); VM4; BAR; QRD(aB, bB, 3); QMFMA(aA, bA);   // tile p+2
        QSTAGE(1, p + 5); VM4; BAR; QRD(aA, bA, 0); QMFMA(aB, bB);   // tile p+3
    }
    // tail phases 60..63
    QSTAGE(2, 62); VM4; BAR; QRD(aB, bB, 1); QMFMA(aA, bA);          // tile 60
    QSTAGE(3, 63); VM4; BAR; QRD(aA, bA, 2); QMFMA(aB, bB);          // tile 61
    VM0; BAR;                QRD(aB, bB, 3); QMFMA(aA, bA);          // tile 62
    QMFMA(aB, bB);                                                   // tile 63

    // ---- epilogue: bias + bf16 store to blocked (B,NH,S,HD) ----
    float bcolv[4];
#pragma unroll
    for (int nf = 0; nf < 4; nf++) bcolv[nf] = bias[n0 + wn * 64 + nf * 16 + l15];

    const int mbase = m0 + wm * 128 + quad * 4;
#pragma unroll
    for (int mf = 0; mf < 8; mf++)
#pragma unroll
        for (int nf = 0; nf < 4; nf++) {
            const int n = n0 + wn * 64 + nf * 16 + l15;
            const int hh = n >> 7;
            const int d = n & 127;
#pragma unroll
            for (int r = 0; r < 4; r++) {
                const int m = mbase + mf * 16 + r;
                const int bb = m >> 11;
                const int s = m & (SEQ - 1);
                out[((size_t)(bb * NH + hh) * SEQ + s) * HD + d] =
                    bf16r(acc[mf][nf][r] + bcolv[nf]);
            }
        }
}

// ==================== O-projection: 256x128, BK=32, 3-slot rotation ==========
// R5 schedule (verified): phase q = {VM0; BAR_q; STAGE(tile q+2 ->
// slot (q+2)%3); RD(tile q+1 <- slot (q+1)%3); MFMA(tile q)}.
// Invariant A: tile q+1 staged @ q-1 post-BAR_{q-1}; VM0@q pre-BAR drains
// per-wave -> certified globally at BAR_q (loads ~1 MFMA phase old).
// Invariant B: slot (q+2)%3 holds tile q-1, reads drained by MFMA@q-1 in
// [BAR_{q-1}, BAR_q]; overwrite DMA issues post-BAR_q.
#define OSTAGE(slot, kt) do { \
    const size_t koA = (size_t)((kt) >> 2) * ((size_t)SEQ * HD) + (size_t)((kt) & 3) * 32; \
    const size_t koB = (size_t)(kt) * 32; \
    gl_lds16(Ah + sgA0 + koA, &Ah_s[slot][(w * 32) * 32]); \
    gl_lds16(Ah + sgA0 + 16 * HD + koA, &Ah_s[slot][(w * 32 + 16) * 32]); \
    gl_lds16(Al + sgA0 + koA, &Al_s[slot][(w * 32) * 32]); \
    gl_lds16(Al + sgA0 + 16 * HD + koA, &Al_s[slot][(w * 32 + 16) * 32]); \
    gl_lds16(Bh + sgB0 + koB, &Bh_s[slot][(w * 16) * 32]); \
    gl_lds16(Bl + sgB0 + koB, &Bl_s[slot][(w * 16) * 32]); \
} while (0)

#define ORD(AH, AL, BH, BL, slot) do { \
    _Pragma("unroll") for (int f = 0; f < 4; f++) { \
        AH[f] = *(const bf16x8*)&Ah_s[slot][aro + f * 512 + cco]; \
        AL[f] = *(const bf16x8*)&Al_s[slot][aro + f * 512 + cco]; \
        BH[f] = *(const bf16x8*)&Bh_s[slot][bro + f * 512 + cco]; \
        BL[f] = *(const bf16x8*)&Bl_s[slot][bro + f * 512 + cco]; \
    } \
} while (0)

#define OMFMA(AH, AL, BH, BL) do { PRIO1; \
    _Pragma("unroll") for (int mf = 0; mf < 4; mf++) \
    _Pragma("unroll") for (int nf = 0; nf < 4; nf++) { \
        acc[mf][nf] = __builtin_amdgcn_mfma_f32_16x16x32_bf16( \
            AH[mf], BH[nf], acc[mf][nf], 0, 0, 0); \
        acc[mf][nf] = __builtin_amdgcn_mfma_f32_16x16x32_bf16( \
            AH[mf], BL[nf], acc[mf][nf], 0, 0, 0); \
        acc[mf][nf] = __builtin_amdgcn_mfma_f32_16x16x32_bf16( \
            AL[mf], BH[nf], acc[mf][nf], 0, 0, 0); \
    } PRIO0; } while (0)

__global__ __launch_bounds__(512, 2)
void k_gemm_o2(const ushort_t* __restrict__ Ah, const ushort_t* __restrict__ Al,
               const ushort_t* __restrict__ Bh, const ushort_t* __restrict__ Bl,
               const float* __restrict__ bias, float* __restrict__ out) {
    __shared__ ushort_t Ah_s[3][256 * 32];
    __shared__ ushort_t Al_s[3][256 * 32];
    __shared__ ushort_t Bh_s[3][128 * 32];
    __shared__ ushort_t Bl_s[3][128 * 32];
    const int tid = threadIdx.x;
    const int lane = tid & 63;
    const int w = tid >> 6;        // wave 0..7
    const int wm = w >> 1;         // 0..3 (64 output rows each)
    const int wn = w & 1;          // 0..1 (64 output cols each)
    const int quad = lane >> 4;
    const int l15 = lane & 15;

    // bijective XCD swizzle (256 % 8 == 0)
    int bid = blockIdx.x;
    bid = (bid & 7) * 32 + (bid >> 3);
    const int bx = bid & 15;       // m-block (0..15)
    const int by = bid >> 4;       // n-block (0..15)
    const int m0 = bx << 8;        // 256 rows
    const int n0 = by << 7;        // 128 cols

    // staging addressing (pre-swizzled global col slot, (r>>1)&3 XOR)
    const int lrow4 = lane >> 2;
    const int col8 = (((lane & 3) ^ ((lrow4 >> 1) & 3)) << 3);
    const size_t sgA0 = ((size_t)(m0 >> 11) * NH * SEQ + (size_t)((m0 & (SEQ - 1)) + w * 32 + lrow4)) * HD + col8;
    const size_t sgB0 = (size_t)(n0 + w * 16 + lrow4) * K_DIM + col8;

    // fragment reads
    const int aro = (wm * 64 + l15) * 32;
    const int bro = (wn * 64 + l15) * 32;
    const int cco = ((quad ^ ((l15 >> 1) & 3)) << 3);

    f32x4 acc[4][4];
#pragma unroll
    for (int i = 0; i < 4; i++)
#pragma unroll
        for (int j = 0; j < 4; j++) acc[i][j] = (f32x4){0.f, 0.f, 0.f, 0.f};

    bf16x8 ahA[4], alA[4], bhA[4], blA[4];
    bf16x8 ahB[4], alB[4], bhB[4], blB[4];

    // prologue: tiles 0,1 staged; VM6 pre-BAR certifies tile0 for all waves
    OSTAGE(0, 0);
    OSTAGE(1, 1);
    VM6; BAR;
    ORD(ahA, alA, bhA, blA, 0);

    // phases 0..59 (10 iters x 6 phases; slot/set pattern period 6)
    for (int it = 0; it < 10; ++it) {
        const int q = 6 * it;
        VM0; BAR; OSTAGE(2, q + 2); ORD(ahB, alB, bhB, blB, 1); OMFMA(ahA, alA, bhA, blA);  // tile q
        VM0; BAR; OSTAGE(0, q + 3); ORD(ahA, alA, bhA, blA, 2); OMFMA(ahB, alB, bhB, blB);  // q+1
        VM0; BAR; OSTAGE(1, q + 4); ORD(ahB, alB, bhB, blB, 0); OMFMA(ahA, alA, bhA, blA);  // q+2
        VM0; BAR; OSTAGE(2, q + 5); ORD(ahA, alA, bhA, blA, 1); OMFMA(ahB, alB, bhB, blB);  // q+3
        VM0; BAR; OSTAGE(0, q + 6); ORD(ahB, alB, bhB, blB, 2); OMFMA(ahA, alA, bhA, blA);  // q+4
        VM0; BAR; OSTAGE(1, q + 7); ORD(ahA, alA, bhA, blA, 0); OMFMA(ahB, alB, bhB, blB);  // q+5
    }
    // tail phases 60..63
    VM0; BAR; OSTAGE(2, 62); ORD(ahB, alB, bhB, blB, 1); OMFMA(ahA, alA, bhA, blA);  // tile 60
    VM0; BAR; OSTAGE(0, 63); ORD(ahA, alA, bhA, blA, 2); OMFMA(ahB, alB, bhB, blB);  // tile 61
    VM0; BAR;                ORD(ahB, alB, bhB, blB, 0); OMFMA(ahA, alA, bhA, blA);  // tile 62
    OMFMA(ahB, alB, bhB, blB);                                                        // tile 63

    // ---- epilogue: bias + coalesced fp32 store ----
    float bcolv[4];
#pragma unroll
    for (int nf = 0; nf < 4; nf++) bcolv[nf] = bias[n0 + wn * 64 + nf * 16 + l15];

    const int mb = m0 + wm * 64 + quad * 4;
    const int nb = n0 + wn * 64 + l15;
#pragma unroll
    for (int fm = 0; fm < 4; fm++)
#pragma unroll
        for (int fn = 0; fn < 4; fn++)
#pragma unroll
            for (int r = 0; r < 4; r++)
                out[(size_t)(mb + fm * 16 + r) * HIDDEN + nb + fn * 16] =
                    acc[fm][fn][r] + bcolv[fn];
}

// ========== K-RoPE (vectorized, 8 d-pairs/thread) + V transpose-pack =========
// blocks [0, 2048): K rope, bf16 in/out, u16x8/f32x4 width (G13).
//   threads = 32 bh x 2048 s x 8 octets = 524288. Q-rope moved into flash
//   (thread-local there); Qb intermediate eliminated.
// blocks [2048, 4096): V transpose (B,H,S,D) bf16 -> (B,H,D,S) bf16.
__global__ __launch_bounds__(256)
void k_ropek_vpack(const ushort_t* __restrict__ kb, const ushort_t* __restrict__ vb,
                   const float* __restrict__ ct, const float* __restrict__ st,
                   ushort_t* __restrict__ Kb, ushort_t* __restrict__ vt) {
    __shared__ float t[64][65];
    const int tid = threadIdx.x;
    const int blk = blockIdx.x;
    if (blk < 2048) {
        // ---- K rope, vectorized ----
        int idx = blk * 256 + tid;
        int o = idx & 7;                 // d-octet: d0 = 8*o in [0,64)
        int s = (idx >> 3) & (SEQ - 1);
        int bh = idx >> 14;              // 0..31
        const int d0 = o << 3;
        size_t base = ((size_t)bh * SEQ + s) * HD;
        float c[8], sn[8];
        *(float4*)&c[0]  = *(const float4*)&ct[(s << 6) + d0];
        *(float4*)&c[4]  = *(const float4*)&ct[(s << 6) + d0 + 4];
        *(float4*)&sn[0] = *(const float4*)&st[(s << 6) + d0];
        *(float4*)&sn[4] = *(const float4*)&st[(s << 6) + d0 + 4];
        u16x8 k0 = *(const u16x8*)(kb + base + d0);
        u16x8 k1 = *(const u16x8*)(kb + base + 64 + d0);
        u16x8 lo, hi;
#pragma unroll
        for (int j = 0; j < 8; j++) {
            float a = bf2f(k0[j]), b = bf2f(k1[j]);
            lo[j] = bf16r(a * c[j] - b * sn[j]);
            hi[j] = bf16r(b * c[j] + a * sn[j]);
        }
        *(u16x8*)(Kb + base + d0) = lo;
        *(u16x8*)(Kb + base + 64 + d0) = hi;
    } else {
        // ---- V transpose path ----
        int b = blk - 2048;              // 2048 blocks: (32 s, 2 d, 32 bh)
        const int s0 = (b & 31) << 6;
        const int d0 = ((b >> 5) & 1) << 6;
        const int bh = b >> 6;
        const ushort_t* src = vb + ((size_t)bh * SEQ + s0) * HD + d0;
        const int rr = tid >> 4;
        const int cc = (tid & 15) << 2;
#pragma unroll
        for (int i = 0; i < 4; i++) {
            ushort4 x = *(const ushort4*)(src + (size_t)(i * 16 + rr) * HD + cc);
            t[i * 16 + rr][cc]     = bf2f(x.x);
            t[i * 16 + rr][cc + 1] = bf2f(x.y);
            t[i * 16 + rr][cc + 2] = bf2f(x.z);
            t[i * 16 + rr][cc + 3] = bf2f(x.w);
        }
        __syncthreads();
        const int dr = tid >> 2;
        const int sc_ = (tid & 3) << 4;
        ushort_t* dst = vt + ((size_t)bh * HD + d0 + dr) * SEQ + s0 + sc_;
        u16x8 o0, o1;
#pragma unroll
        for (int u = 0; u < 8; u++) o0[u] = bf16r(t[sc_ + u][dr]);
#pragma unroll
        for (int u = 0; u < 8; u++) o1[u] = bf16r(t[sc_ + 8 + u][dr]);
        *(u16x8*)dst = o0;
        *(u16x8*)(dst + 8) = o1;
    }
}

// ==================== MFMA flash attention v5 ================================
// R8 structure (verified): kv-tile 64, separate K/V/Ps buffers, 2 barriers
// per tile; Ps wave-private (no P barrier).
// R9: Q-rope applied IN-REGISTER at Q-load. Pairs (d, d+64) = fragments
// (ks, ks+2) of the SAME thread: rot is thread-local VALU, once per block.
// Reads pre-rope qb directly (Qb intermediate eliminated); scq folded here.
// Math pipeline identical to the old rope kernel (bf16->f32->rope->bf16).
__global__ __launch_bounds__(256, 2)
void k_flash_mfma(const ushort_t* __restrict__ Qb, const ushort_t* __restrict__ Kb,
                  const ushort_t* __restrict__ Vt,
                  const float* __restrict__ ct, const float* __restrict__ st,
                  ushort_t* __restrict__ ch, ushort_t* __restrict__ cl) {
    __shared__ ushort_t SH[27136];      // Ks @0 (8704) | Vs @8704 (9216) | Ps @17920 (9216)
    ushort_t* Ks = SH;
    ushort_t* Vs = SH + 8704;
    ushort_t* Ps = SH + 17920;
    const int tid = threadIdx.x;
    const int lane = tid & 63;
    const int w = tid >> 6;
    const int quad = lane >> 4;
    const int l15 = lane & 15;
    const int bi = blockIdx.x;
    const int bh = bi & 31;              // XCD swizzle: bh%8 == XCD id
    const int qt = bi >> 5;              // 0..15 (128 q rows each)
    const ushort_t* Qg = Qb + ((size_t)bh * SEQ + ((size_t)qt << 7)) * HD;
    const ushort_t* Kg = Kb + (size_t)bh * SEQ * HD;
    const ushort_t* Vg = Vt + (size_t)bh * HD * SEQ;

    // persistent Q fragments (B-operand), roped in-register.
    // Row sg = qt*128 + w*32 + qi*16 + l15; d = ks*32 + quad*8 + j.
    // ks in {0,1}: d<64, pair at ks+2; table idx (sg<<6) + ks*32 + quad*8 + j.
    const float scq = 0.08838834764831845f;
    bf16x8 qf[2][4];
#pragma unroll
    for (int qi = 0; qi < 2; qi++) {
        const int row = w * 32 + qi * 16 + l15;
        const int sg = (qt << 7) + row;
        const int tb = (sg << 6) + quad * 8;
        float c0[8], s0[8], c1[8], s1[8];
        *(float4*)&c0[0] = *(const float4*)&ct[tb];
        *(float4*)&c0[4] = *(const float4*)&ct[tb + 4];
        *(float4*)&s0[0] = *(const float4*)&st[tb];
        *(float4*)&s0[4] = *(const float4*)&st[tb + 4];
        *(float4*)&c1[0] = *(const float4*)&ct[tb + 32];
        *(float4*)&c1[4] = *(const float4*)&ct[tb + 36];
        *(float4*)&s1[0] = *(const float4*)&st[tb + 32];
        *(float4*)&s1[4] = *(const float4*)&st[tb + 36];
        const ushort_t* qrow = Qg + (size_t)row * HD + quad * 8;
        u16x8 r0 = *(const u16x8*)(qrow);
        u16x8 r1 = *(const u16x8*)(qrow + 32);
        u16x8 r2 = *(const u16x8*)(qrow + 64);
        u16x8 r3 = *(const u16x8*)(qrow + 96);
        u16x8 f0, f1, f2, f3;
#pragma unroll
        for (int j = 0; j < 8; j++) {
            float a0 = bf2f(r0[j]), a1 = bf2f(r1[j]);
            float a2 = bf2f(r2[j]), a3 = bf2f(r3[j]);
            f0[j] = bf16r((a0 * c0[j] - a2 * s0[j]) * scq);
            f2[j] = bf16r((a2 * c0[j] + a0 * s0[j]) * scq);
            f1[j] = bf16r((a1 * c1[j] - a3 * s1[j]) * scq);
            f3[j] = bf16r((a3 * c1[j] + a1 * s1[j]) * scq);
        }
        qf[qi][0] = __builtin_bit_cast(bf16x8, f0);
        qf[qi][1] = __builtin_bit_cast(bf16x8, f1);
        qf[qi][2] = __builtin_bit_cast(bf16x8, f2);
        qf[qi][3] = __builtin_bit_cast(bf16x8, f3);
    }

    const int sr = tid >> 4;            // K staging row 0..15
    const int sc8 = (tid & 15) << 3;    // K staging col (16B)
    const int vr = tid >> 3;            // V staging row 0..31
    const int vc8 = (tid & 7) << 3;     // V staging col (16B)

    // prefetch tile 0: K rows [0,64), V^T cols [0,64)
    u16x8 Kreg[4], Vreg[4];
#pragma unroll
    for (int i = 0; i < 4; i++)
        Kreg[i] = *(const u16x8*)(Kg + (size_t)(i * 16 + sr) * HD + sc8);
#pragma unroll
    for (int i = 0; i < 4; i++)
        Vreg[i] = *(const u16x8*)(Vg + (size_t)(i * 32 + vr) * SEQ + vc8);

    f32x4 acc[2][8];
#pragma unroll
    for (int qi = 0; qi < 2; qi++)
#pragma unroll
        for (int d = 0; d < 8; d++) acc[qi][d] = (f32x4){0.f, 0.f, 0.f, 0.f};
    float lp[2] = {0.f, 0.f};

    for (int kt = 0; kt < SEQ; kt += 64) {
        const int np = kt + 64;
        __syncthreads();                // prev tile's kf/vf/pf reads done
#pragma unroll
        for (int i = 0; i < 4; i++)     // stage K tile
            *(u16x8*)&Ks[(i * 16 + sr) * 136 + sc8] = Kreg[i];
#pragma unroll
        for (int i = 0; i < 4; i++)     // stage V tile
            *(u16x8*)&Vs[(i * 32 + vr) * 72 + vc8] = Vreg[i];
        if (np < SEQ) {
#pragma unroll
            for (int i = 0; i < 4; i++)
                Kreg[i] = *(const u16x8*)(Kg + (size_t)(np + i * 16 + sr) * HD + sc8);
#pragma unroll
            for (int i = 0; i < 4; i++)
                Vreg[i] = *(const u16x8*)(Vg + (size_t)(i * 32 + vr) * SEQ + np + vc8);
        }
        __syncthreads();                // staging visible block-wide

        // ---- QK^T: sc[qi][j] = K(16 rows) x Q(16 rows)^T ----
        f32x4 sc[2][4];
#pragma unroll
        for (int qi = 0; qi < 2; qi++)
#pragma unroll
            for (int j = 0; j < 4; j++) sc[qi][j] = (f32x4){0.f, 0.f, 0.f, 0.f};
#pragma unroll
        for (int ks = 0; ks < 4; ks++) {
            bf16x8 kf[4];
#pragma unroll
            for (int j = 0; j < 4; j++)
                kf[j] = *(const bf16x8*)&Ks[(j * 16 + l15) * 136 + ks * 32 + quad * 8];
#pragma unroll
            for (int qi = 0; qi < 2; qi++)
#pragma unroll
                for (int j = 0; j < 4; j++)
                    sc[qi][j] = __builtin_amdgcn_mfma_f32_16x16x32_bf16(
                        kf[j], qf[qi][ks], sc[qi][j], 0, 0, 0);
        }

        // ---- p = exp(score); accumulate l; write P (wave-private rows) ----
#pragma unroll
        for (int qi = 0; qi < 2; qi++) {
            const int prow = (w * 32 + qi * 16 + l15) * 72 + quad * 4;
#pragma unroll
            for (int j = 0; j < 4; j++) {
                float p0 = __expf(sc[qi][j][0]);
                float p1 = __expf(sc[qi][j][1]);
                float p2 = __expf(sc[qi][j][2]);
                float p3 = __expf(sc[qi][j][3]);
                lp[qi] += (p0 + p1) + (p2 + p3);
                __hip_bfloat162 lo2 = __float22bfloat162_rn({p0, p1});
                __hip_bfloat162 hi2 = __float22bfloat162_rn({p2, p3});
                uint2 pk = make_uint2(*(u32*)&lo2, *(u32*)&hi2);
                *(uint2*)&Ps[prow + j * 16] = pk;
            }
        }

        // ---- PV: acc[qi][db] += V^T(16 d-rows) x P^T ----
#pragma unroll
        for (int ks = 0; ks < 2; ks++) {
            bf16x8 pf[2];
#pragma unroll
            for (int qi = 0; qi < 2; qi++)
                pf[qi] = *(const bf16x8*)&Ps[(w * 32 + qi * 16 + l15) * 72 + ks * 32 + quad * 8];
#pragma unroll
            for (int db = 0; db < 8; db++) {
                bf16x8 vf = *(const bf16x8*)&Vs[(db * 16 + l15) * 72 + ks * 32 + quad * 8];
#pragma unroll
                for (int qi = 0; qi < 2; qi++)
                    acc[qi][db] = __builtin_amdgcn_mfma_f32_16x16x32_bf16(vf, pf[qi], acc[qi][db], 0, 0, 0);
            }
        }
    }

    // ---- epilogue: l-reduce, normalize, re-layout via SH, coalesced store ----
    float inv[2];
#pragma unroll
    for (int qi = 0; qi < 2; qi++) {
        float l = lp[qi];
        l += __shfl_xor(l, 16);
        l += __shfl_xor(l, 32);
        inv[qi] = 1.0f / l;
    }
    const size_t obase = ((size_t)bh * SEQ + ((size_t)qt << 7)) * HD;

    __syncthreads();                    // final PV reads of Vs/Ps done
    // hi pass (SH reused as [128][136] scratch)
#pragma unroll
    for (int qi = 0; qi < 2; qi++)
#pragma unroll
        for (int db = 0; db < 8; db++) {
            ushort4 hh;
            ushort_t dum;
            split1(acc[qi][db][0] * inv[qi], hh.x, dum);
            split1(acc[qi][db][1] * inv[qi], hh.y, dum);
            split1(acc[qi][db][2] * inv[qi], hh.z, dum);
            split1(acc[qi][db][3] * inv[qi], hh.w, dum);
            *(ushort4*)&SH[(w * 32 + qi * 16 + l15) * 136 + db * 16 + quad * 4] = hh;
        }
    __syncthreads();
#pragma unroll
    for (int t2 = 0; t2 < 8; t2++) {
        int c = t2 * 256 + tid;
        int row = c >> 4, col8 = (c & 15) << 3;
        *(u16x8*)&ch[obase + (size_t)row * HD + col8] = *(const u16x8*)&SH[row * 136 + col8];
    }
    __syncthreads();
    // lo pass
#pragma unroll
    for (int qi = 0; qi < 2; qi++)
#pragma unroll
        for (int db = 0; db < 8; db++) {
            ushort4 ll;
            ushort_t dum;
            split1(acc[qi][db][0] * inv[qi], dum, ll.x);
            split1(acc[qi][db][1] * inv[qi], dum, ll.y);
            split1(acc[qi][db][2] * inv[qi], dum, ll.z);
            split1(acc[qi][db][3] * inv[qi], dum, ll.w);
            *(ushort4*)&SH[(w * 32 + qi * 16 + l15) * 136 + db * 16 + quad * 4] = ll;
        }
    __syncthreads();
#pragma unroll
    for (int t2 = 0; t2 < 8; t2++) {
        int c = t2 * 256 + tid;
        int row = c >> 4, col8 = (c & 15) << 3;
        *(u16x8*)&cl[obase + (size_t)row * HD + col8] = *(const u16x8*)&SH[row * 136 + col8];
    }
}

// ==================== launch =================================================
extern "C" void kernel_launch(void* const* d_in, const int* in_sizes, int n_in,
                              void* d_out, int out_size, void* d_ws, size_t ws_size,
                              hipStream_t stream) {
    const float* X  = (const float*)d_in[0];
    const float* Wq = (const float*)d_in[1];
    const float* bq = (const float*)d_in[2];
    const float* Wk = (const float*)d_in[3];
    const float* bk = (const float*)d_in[4];
    const float* Wv = (const float*)d_in[5];
    const float* bv = (const float*)d_in[6];
    const float* Wo = (const float*)d_in[7];
    const float* bo = (const float*)d_in[8];
    float* out = (float*)d_out;

    const size_t QS = (size_t)NB * NH * SEQ * HD;   // 8,388,608 elems
    const size_t WS = (size_t)HIDDEN * HIDDEN;      // 4,194,304 elems
    ushort_t* qb_ws = (ushort_t*)d_ws;              // bf16 blocked QKV outputs
    ushort_t* kb_ws = qb_ws + QS;
    ushort_t* vb_ws = kb_ws + QS;
    float* cost = (float*)(vb_ws + QS);
    float* sint = cost + (size_t)SEQ * 64;
    ushort_t* Xh = (ushort_t*)(sint + (size_t)SEQ * 64);
    ushort_t* Wh0 = Xh + QS;
    ushort_t* Wh1 = Wh0 + WS;
    ushort_t* Wh2 = Wh1 + WS;
    ushort_t* Woh = Wh2 + WS;
    ushort_t* Wol = Woh + WS;
    ushort_t* Kb  = Wol + WS;
    ushort_t* Vtb = Kb + QS;
    ushort_t* ctxh = Xh;                            // Xh dead after qkv8
    ushort_t* ctxl = kb_ws;                         // kb_ws dead after ropek

    k_cvt_all<<<TBLK + (XG + 4 * WG) / 256, 256, 0, stream>>>(
        (const float4*)X, (const float4*)Wq, (const float4*)Wk, (const float4*)Wv,
        (const float4*)Wo,
        (ushort4*)Xh, (ushort4*)Wh0, (ushort4*)Wh1, (ushort4*)Wh2,
        (ushort4*)Woh, (ushort4*)Wol, cost, sint);

    k_gemm_qkv8<<<384, 512, 0, stream>>>(Xh, Wh0, Wh1, Wh2, bq, bk, bv,
                                         qb_ws, kb_ws, vb_ws);

    k_ropek_vpack<<<4096, 256, 0, stream>>>(kb_ws, vb_ws, cost, sint, Kb, Vtb);

    k_flash_mfma<<<512, 256, 0, stream>>>(qb_ws, Kb, Vtb, cost, sint, ctxh, ctxl);

    k_gemm_o2<<<dim3(256), 512, 0, stream>>>(ctxh, ctxl, Woh, Wol, bo, out);
}

// Round 10
// 443.139 us; speedup vs baseline: 1.1595x; 1.0080x over previous
//
#include <hip/hip_runtime.h>
#include <hip/hip_bf16.h>
#include <math.h>

#define HIDDEN 2048
#define NH 16
#define HD 128
#define NB 2
#define SEQ 2048
#define K_DIM 2048

typedef unsigned int u32;
typedef unsigned short ushort_t;
typedef __bf16 bf16x8 __attribute__((ext_vector_type(8)));
typedef float f32x4 __attribute__((ext_vector_type(4)));
typedef ushort_t u16x8 __attribute__((ext_vector_type(8)));

// ---------- fp32 -> (bf16 hi, bf16 lo) split, RNE both halves ----------
__device__ __forceinline__ void split1(float x, unsigned short& h, unsigned short& l) {
    u32 u = __float_as_uint(x);
    u32 hr = (u + 0x7FFFu + ((u >> 16) & 1u)) >> 16;
    h = (unsigned short)hr;
    float r = x - __uint_as_float(hr << 16);
    u32 u2 = __float_as_uint(r);
    l = (unsigned short)((u2 + 0x7FFFu + ((u2 >> 16) & 1u)) >> 16);
}

__device__ __forceinline__ ushort_t bf16r(float x) {
    u32 u = __float_as_uint(x);
    return (ushort_t)((u + 0x7FFFu + ((u >> 16) & 1u)) >> 16);
}

__device__ __forceinline__ float bf2f(ushort_t u) {
    return __uint_as_float(((u32)u) << 16);
}

__device__ __forceinline__ void gl_lds16(const void* g, void* l) {
    __builtin_amdgcn_global_load_lds(
        (const __attribute__((address_space(1))) u32*)g,
        (__attribute__((address_space(3))) u32*)l, 16, 0, 0);
}

// ====== fused: RoPE tables (blocks 0..511) + fp32->bf16 conversions ==========
#define XG 2097152   // X float4 groups
#define WG 1048576   // W float4 groups
#define TBLK 512     // table blocks (SEQ*64 threads)
__global__ void k_cvt_all(const float4* __restrict__ X, const float4* __restrict__ W0,
                          const float4* __restrict__ W1, const float4* __restrict__ W2,
                          const float4* __restrict__ Wo,
                          ushort4* __restrict__ Xh, ushort4* __restrict__ H0,
                          ushort4* __restrict__ H1, ushort4* __restrict__ H2,
                          ushort4* __restrict__ WoH, ushort4* __restrict__ WoL,
                          float* __restrict__ ct, float* __restrict__ st) {
    const int blk = blockIdx.x;
    if (blk < TBLK) {
        int idx = blk * 256 + threadIdx.x;    // SEQ*64 threads
        int s = idx >> 6, d = idx & 63;
        double inv = pow(10000.0, -(double)d * (1.0 / 64.0));
        double ang = (double)s * inv;
        ct[idx] = (float)cos(ang);
        st[idx] = (float)sin(ang);
        return;
    }
    int idx = (blk - TBLK) * 256 + threadIdx.x;   // XG + 4*WG threads
    if (idx < XG + 3 * WG) {
        const float4* src;
        ushort4* dst;
        int off;
        if (idx < XG) { src = X; dst = Xh; off = idx; }
        else {
            int t = idx - XG;
            int m = t >> 20;        // WG = 2^20
            off = t & (WG - 1);
            src = (m == 0) ? W0 : (m == 1) ? W1 : W2;
            dst = (m == 0) ? H0 : (m == 1) ? H1 : H2;
        }
        float4 x = src[off];
        ushort4 h;
        h.x = bf16r(x.x); h.y = bf16r(x.y); h.z = bf16r(x.z); h.w = bf16r(x.w);
        dst[off] = h;
    } else {
        int off = idx - XG - 3 * WG;
        float4 x = Wo[off];
        ushort4 h, l;
        split1(x.x, h.x, l.x);
        split1(x.y, h.y, l.y);
        split1(x.z, h.z, l.z);
        split1(x.w, h.w, l.w);
        WoH[off] = h;
        WoL[off] = l;
    }
}

// ==================== common waitcnt/barrier macros ==========================
#define BAR  __builtin_amdgcn_s_barrier()
#define VM6  asm volatile("s_waitcnt vmcnt(6)" ::: "memory")
#define VM4  asm volatile("s_waitcnt vmcnt(4)" ::: "memory")
#define VM0  asm volatile("s_waitcnt vmcnt(0)" ::: "memory")
#define PRIO1 __builtin_amdgcn_s_setprio(1)
#define PRIO0 __builtin_amdgcn_s_setprio(0)

// ==================== fused QKV: 256x256, BK=32, 4-slot rotation =============
// R5 schedule (verified): phase p = {STAGE(tile p+2 -> slot (p+2)&3); VM4;
// BAR_p; RD(tile p+1 -> other reg set); MFMA(tile p on current set)}.
// Invariant A (gate): VM4 pre-BAR -> at BAR_p every wave certified its
// tile-(p+1) loads complete. Invariant B: stage@p targets slot of tile p-2,
// reads drained by MFMA@p-1 before BAR_{p-1} < overwrite issue. S=4 >= L+2.
// Epilogue writes bf16 directly (halves write traffic vs fp32).
#define QSTAGE(slot, kt) do { \
    const ushort_t* gA_ = Xh + sgA + (size_t)(kt) * 32; \
    gl_lds16(gA_, &As[slot][(w * 32) * 32]); \
    gl_lds16(gA_ + 16 * 2048, &As[slot][(w * 32 + 16) * 32]); \
    const ushort_t* gB_ = Wsel + sgB + (size_t)(kt) * 32; \
    gl_lds16(gB_, &Bs[slot][(w * 32) * 32]); \
    gl_lds16(gB_ + 16 * 2048, &Bs[slot][(w * 32 + 16) * 32]); \
} while (0)

#define QRD(AD, BD, slot) do { \
    _Pragma("unroll") for (int mf = 0; mf < 8; mf++) \
        AD[mf] = *(const bf16x8*)&As[slot][arow + mf * 512 + ccq]; \
    _Pragma("unroll") for (int nf = 0; nf < 4; nf++) \
        BD[nf] = *(const bf16x8*)&Bs[slot][brow + nf * 512 + ccq]; \
} while (0)

#define QMFMA(AD, BD) do { PRIO1; \
    _Pragma("unroll") for (int mf = 0; mf < 8; mf++) \
    _Pragma("unroll") for (int nf = 0; nf < 4; nf++) \
        acc[mf][nf] = __builtin_amdgcn_mfma_f32_16x16x32_bf16( \
            AD[mf], BD[nf], acc[mf][nf], 0, 0, 0); \
    PRIO0; } while (0)

__global__ __launch_bounds__(512, 2)
void k_gemm_qkv8(const ushort_t* __restrict__ Xh,
                 const ushort_t* __restrict__ W0, const ushort_t* __restrict__ W1,
                 const ushort_t* __restrict__ W2,
                 const float* __restrict__ b0, const float* __restrict__ b1,
                 const float* __restrict__ b2,
                 ushort_t* __restrict__ o0, ushort_t* __restrict__ o1,
                 ushort_t* __restrict__ o2) {
    __shared__ ushort_t As[4][256 * 32];
    __shared__ ushort_t Bs[4][256 * 32];
    const int tid = threadIdx.x;
    const int lane = tid & 63;
    const int w = tid >> 6;        // wave 0..7
    const int wm = w >> 2;         // 0..1  (128 output rows each)
    const int wn = w & 3;          // 0..3  (64 output cols each)
    const int quad = lane >> 4;
    const int l15 = lane & 15;

    // bijective XCD swizzle (384 % 8 == 0)
    int bid = blockIdx.x;
    bid = (bid & 7) * 48 + (bid >> 3);
    const int bx = bid & 15;       // m-block
    const int by = bid >> 4;       // 0..23
    const int m0 = bx << 8;
    const int mat = by >> 3;
    const int n0 = (by & 7) << 8;
    const ushort_t* Wsel = (mat == 0) ? W0 : (mat == 1) ? W1 : W2;
    const float* bias = (mat == 0) ? b0 : (mat == 1) ? b1 : b2;
    ushort_t* out = (mat == 0) ? o0 : (mat == 1) ? o1 : o2;

    // staging: wave w covers rows [w*32, w*32+32); lane -> (row lrow4, slot
    // lane&3); global col slot pre-swizzled.
    const int lrow4 = lane >> 2;
    const int col8 = (((lane & 3) ^ ((lrow4 >> 1) & 3)) << 3);
    const size_t sgA = (size_t)(m0 + w * 32 + lrow4) * 2048 + col8;
    const size_t sgB = (size_t)(n0 + w * 32 + lrow4) * 2048 + col8;

    // fragment reads: row R wants global slot q -> LDS slot q^((R>>1)&3)
    const int arow = (wm * 128 + l15) * 32;
    const int brow = (wn * 64 + l15) * 32;
    const int ccq = ((quad ^ ((l15 >> 1) & 3)) << 3);

    f32x4 acc[8][4];
#pragma unroll
    for (int i = 0; i < 8; i++)
#pragma unroll
        for (int j = 0; j < 4; j++) acc[i][j] = (f32x4){0.f, 0.f, 0.f, 0.f};

    bf16x8 aA[8], bA[4], aB[8], bB[4];

    // prologue: tiles 0,1 staged; VM4 pre-BAR certifies tile0 for all waves
    QSTAGE(0, 0); QSTAGE(1, 1);
    VM4; BAR;
    QRD(aA, bA, 0);

    // phases 0..59 (15 iters x 4 phases; slots compile-time constants)
    for (int p = 0; p < 60; p += 4) {
        QSTAGE(2, p + 2); VM4; BAR; QRD(aB, bB, 1); QMFMA(aA, bA);   // tile p
        QSTAGE(3, p + 3); VM4; BAR; QRD(aA, bA, 2); QMFMA(aB, bB);   // tile p+1
        QSTAGE(0, p + 4); VM4; BAR; QRD(aB, bB, 3); QMFMA(aA, bA);   // tile p+2
        QSTAGE(1, p + 5); VM4; BAR; QRD(aA, bA, 0); QMFMA(aB, bB);   // tile p+3
    }
    // tail phases 60..63
    QSTAGE(2, 62); VM4; BAR; QRD(aB, bB, 1); QMFMA(aA, bA);          // tile 60
    QSTAGE(3, 63); VM4; BAR; QRD(aA, bA, 2); QMFMA(aB, bB);          // tile 61
    VM0; BAR;                QRD(aB, bB, 3); QMFMA(aA, bA);          // tile 62
    QMFMA(aB, bB);                                                   // tile 63

    // ---- epilogue: bias + bf16 store to blocked (B,NH,S,HD) ----
    float bcolv[4];
#pragma unroll
    for (int nf = 0; nf < 4; nf++) bcolv[nf] = bias[n0 + wn * 64 + nf * 16 + l15];

    const int mbase = m0 + wm * 128 + quad * 4;
#pragma unroll
    for (int mf = 0; mf < 8; mf++)
#pragma unroll
        for (int nf = 0; nf < 4; nf++) {
            const int n = n0 + wn * 64 + nf * 16 + l15;
            const int hh = n >> 7;
            const int d = n & 127;
#pragma unroll
            for (int r = 0; r < 4; r++) {
                const int m = mbase + mf * 16 + r;
                const int bb = m >> 11;
                const int s = m & (SEQ - 1);
                out[((size_t)(bb * NH + hh) * SEQ + s) * HD + d] =
                    bf16r(acc[mf][nf][r] + bcolv[nf]);
            }
        }
}

// ==================== O-projection: 256x128, BK=32, 3-slot rotation ==========
// R5 schedule (verified): phase q = {VM0; BAR_q; STAGE(tile q+2 ->
// slot (q+2)%3); RD(tile q+1 <- slot (q+1)%3); MFMA(tile q)}.
// Invariant A: tile q+1 staged @ q-1 post-BAR_{q-1}; VM0@q pre-BAR drains
// per-wave -> certified globally at BAR_q (loads ~1 MFMA phase old).
// Invariant B: slot (q+2)%3 holds tile q-1, reads drained by MFMA@q-1 in
// [BAR_{q-1}, BAR_q]; overwrite DMA issues post-BAR_q.
#define OSTAGE(slot, kt) do { \
    const size_t koA = (size_t)((kt) >> 2) * ((size_t)SEQ * HD) + (size_t)((kt) & 3) * 32; \
    const size_t koB = (size_t)(kt) * 32; \
    gl_lds16(Ah + sgA0 + koA, &Ah_s[slot][(w * 32) * 32]); \
    gl_lds16(Ah + sgA0 + 16 * HD + koA, &Ah_s[slot][(w * 32 + 16) * 32]); \
    gl_lds16(Al + sgA0 + koA, &Al_s[slot][(w * 32) * 32]); \
    gl_lds16(Al + sgA0 + 16 * HD + koA, &Al_s[slot][(w * 32 + 16) * 32]); \
    gl_lds16(Bh + sgB0 + koB, &Bh_s[slot][(w * 16) * 32]); \
    gl_lds16(Bl + sgB0 + koB, &Bl_s[slot][(w * 16) * 32]); \
} while (0)

#define ORD(AH, AL, BH, BL, slot) do { \
    _Pragma("unroll") for (int f = 0; f < 4; f++) { \
        AH[f] = *(const bf16x8*)&Ah_s[slot][aro + f * 512 + cco]; \
        AL[f] = *(const bf16x8*)&Al_s[slot][aro + f * 512 + cco]; \
        BH[f] = *(const bf16x8*)&Bh_s[slot][bro + f * 512 + cco]; \
        BL[f] = *(const bf16x8*)&Bl_s[slot][bro + f * 512 + cco]; \
    } \
} while (0)

#define OMFMA(AH, AL, BH, BL) do { PRIO1; \
    _Pragma("unroll") for (int mf = 0; mf < 4; mf++) \
    _Pragma("unroll") for (int nf = 0; nf < 4; nf++) { \
        acc[mf][nf] = __builtin_amdgcn_mfma_f32_16x16x32_bf16( \
            AH[mf], BH[nf], acc[mf][nf], 0, 0, 0); \
        acc[mf][nf] = __builtin_amdgcn_mfma_f32_16x16x32_bf16( \
            AH[mf], BL[nf], acc[mf][nf], 0, 0, 0); \
        acc[mf][nf] = __builtin_amdgcn_mfma_f32_16x16x32_bf16( \
            AL[mf], BH[nf], acc[mf][nf], 0, 0, 0); \
    } PRIO0; } while (0)

__global__ __launch_bounds__(512, 2)
void k_gemm_o2(const ushort_t* __restrict__ Ah, const ushort_t* __restrict__ Al,
               const ushort_t* __restrict__ Bh, const ushort_t* __restrict__ Bl,
               const float* __restrict__ bias, float* __restrict__ out) {
    __shared__ ushort_t Ah_s[3][256 * 32];
    __shared__ ushort_t Al_s[3][256 * 32];
    __shared__ ushort_t Bh_s[3][128 * 32];
    __shared__ ushort_t Bl_s[3][128 * 32];
    const int tid = threadIdx.x;
    const int lane = tid & 63;
    const int w = tid >> 6;        // wave 0..7
    const int wm = w >> 1;         // 0..3 (64 output rows each)
    const int wn = w & 1;          // 0..1 (64 output cols each)
    const int quad = lane >> 4;
    const int l15 = lane & 15;

    // bijective XCD swizzle (256 % 8 == 0)
    int bid = blockIdx.x;
    bid = (bid & 7) * 32 + (bid >> 3);
    const int bx = bid & 15;       // m-block (0..15)
    const int by = bid >> 4;       // n-block (0..15)
    const int m0 = bx << 8;        // 256 rows
    const int n0 = by << 7;        // 128 cols

    // staging addressing (pre-swizzled global col slot, (r>>1)&3 XOR)
    const int lrow4 = lane >> 2;
    const int col8 = (((lane & 3) ^ ((lrow4 >> 1) & 3)) << 3);
    const size_t sgA0 = ((size_t)(m0 >> 11) * NH * SEQ + (size_t)((m0 & (SEQ - 1)) + w * 32 + lrow4)) * HD + col8;
    const size_t sgB0 = (size_t)(n0 + w * 16 + lrow4) * K_DIM + col8;

    // fragment reads
    const int aro = (wm * 64 + l15) * 32;
    const int bro = (wn * 64 + l15) * 32;
    const int cco = ((quad ^ ((l15 >> 1) & 3)) << 3);

    f32x4 acc[4][4];
#pragma unroll
    for (int i = 0; i < 4; i++)
#pragma unroll
        for (int j = 0; j < 4; j++) acc[i][j] = (f32x4){0.f, 0.f, 0.f, 0.f};

    bf16x8 ahA[4], alA[4], bhA[4], blA[4];
    bf16x8 ahB[4], alB[4], bhB[4], blB[4];

    // prologue: tiles 0,1 staged; VM6 pre-BAR certifies tile0 for all waves
    OSTAGE(0, 0);
    OSTAGE(1, 1);
    VM6; BAR;
    ORD(ahA, alA, bhA, blA, 0);

    // phases 0..59 (10 iters x 6 phases; slot/set pattern period 6)
    for (int it = 0; it < 10; ++it) {
        const int q = 6 * it;
        VM0; BAR; OSTAGE(2, q + 2); ORD(ahB, alB, bhB, blB, 1); OMFMA(ahA, alA, bhA, blA);  // tile q
        VM0; BAR; OSTAGE(0, q + 3); ORD(ahA, alA, bhA, blA, 2); OMFMA(ahB, alB, bhB, blB);  // q+1
        VM0; BAR; OSTAGE(1, q + 4); ORD(ahB, alB, bhB, blB, 0); OMFMA(ahA, alA, bhA, blA);  // q+2
        VM0; BAR; OSTAGE(2, q + 5); ORD(ahA, alA, bhA, blA, 1); OMFMA(ahB, alB, bhB, blB);  // q+3
        VM0; BAR; OSTAGE(0, q + 6); ORD(ahB, alB, bhB, blB, 2); OMFMA(ahA, alA, bhA, blA);  // q+4
        VM0; BAR; OSTAGE(1, q + 7); ORD(ahA, alA, bhA, blA, 0); OMFMA(ahB, alB, bhB, blB);  // q+5
    }
    // tail phases 60..63
    VM0; BAR; OSTAGE(2, 62); ORD(ahB, alB, bhB, blB, 1); OMFMA(ahA, alA, bhA, blA);  // tile 60
    VM0; BAR; OSTAGE(0, 63); ORD(ahA, alA, bhA, blA, 2); OMFMA(ahB, alB, bhB, blB);  // tile 61
    VM0; BAR;                ORD(ahB, alB, bhB, blB, 0); OMFMA(ahA, alA, bhA, blA);  // tile 62
    OMFMA(ahB, alB, bhB, blB);                                                        // tile 63

    // ---- epilogue: bias + coalesced fp32 store ----
    float bcolv[4];
#pragma unroll
    for (int nf = 0; nf < 4; nf++) bcolv[nf] = bias[n0 + wn * 64 + nf * 16 + l15];

    const int mb = m0 + wm * 64 + quad * 4;
    const int nb = n0 + wn * 64 + l15;
#pragma unroll
    for (int fm = 0; fm < 4; fm++)
#pragma unroll
        for (int fn = 0; fn < 4; fn++)
#pragma unroll
            for (int r = 0; r < 4; r++)
                out[(size_t)(mb + fm * 16 + r) * HIDDEN + nb + fn * 16] =
                    acc[fm][fn][r] + bcolv[fn];
}

// ========== K-RoPE (vectorized, 8 d-pairs/thread) + V transpose-pack =========
// blocks [0, 2048): K rope, bf16 in/out, u16x8/f32x4 width (G13).
// blocks [2048, 4096): V transpose (B,H,S,D) bf16 -> (B,H,D,S) bf16.
__global__ __launch_bounds__(256)
void k_ropek_vpack(const ushort_t* __restrict__ kb, const ushort_t* __restrict__ vb,
                   const float* __restrict__ ct, const float* __restrict__ st,
                   ushort_t* __restrict__ Kb, ushort_t* __restrict__ vt) {
    __shared__ float t[64][65];
    const int tid = threadIdx.x;
    const int blk = blockIdx.x;
    if (blk < 2048) {
        // ---- K rope, vectorized ----
        int idx = blk * 256 + tid;
        int o = idx & 7;                 // d-octet: d0 = 8*o in [0,64)
        int s = (idx >> 3) & (SEQ - 1);
        int bh = idx >> 14;              // 0..31
        const int d0 = o << 3;
        size_t base = ((size_t)bh * SEQ + s) * HD;
        float c[8], sn[8];
        *(float4*)&c[0]  = *(const float4*)&ct[(s << 6) + d0];
        *(float4*)&c[4]  = *(const float4*)&ct[(s << 6) + d0 + 4];
        *(float4*)&sn[0] = *(const float4*)&st[(s << 6) + d0];
        *(float4*)&sn[4] = *(const float4*)&st[(s << 6) + d0 + 4];
        u16x8 k0 = *(const u16x8*)(kb + base + d0);
        u16x8 k1 = *(const u16x8*)(kb + base + 64 + d0);
        u16x8 lo, hi;
#pragma unroll
        for (int j = 0; j < 8; j++) {
            float a = bf2f(k0[j]), b = bf2f(k1[j]);
            lo[j] = bf16r(a * c[j] - b * sn[j]);
            hi[j] = bf16r(b * c[j] + a * sn[j]);
        }
        *(u16x8*)(Kb + base + d0) = lo;
        *(u16x8*)(Kb + base + 64 + d0) = hi;
    } else {
        // ---- V transpose path ----
        int b = blk - 2048;              // 2048 blocks: (32 s, 2 d, 32 bh)
        const int s0 = (b & 31) << 6;
        const int d0 = ((b >> 5) & 1) << 6;
        const int bh = b >> 6;
        const ushort_t* src = vb + ((size_t)bh * SEQ + s0) * HD + d0;
        const int rr = tid >> 4;
        const int cc = (tid & 15) << 2;
#pragma unroll
        for (int i = 0; i < 4; i++) {
            ushort4 x = *(const ushort4*)(src + (size_t)(i * 16 + rr) * HD + cc);
            t[i * 16 + rr][cc]     = bf2f(x.x);
            t[i * 16 + rr][cc + 1] = bf2f(x.y);
            t[i * 16 + rr][cc + 2] = bf2f(x.z);
            t[i * 16 + rr][cc + 3] = bf2f(x.w);
        }
        __syncthreads();
        const int dr = tid >> 2;
        const int sc_ = (tid & 3) << 4;
        ushort_t* dst = vt + ((size_t)bh * HD + d0 + dr) * SEQ + s0 + sc_;
        u16x8 o0, o1;
#pragma unroll
        for (int u = 0; u < 8; u++) o0[u] = bf16r(t[sc_ + u][dr]);
#pragma unroll
        for (int u = 0; u < 8; u++) o1[u] = bf16r(t[sc_ + 8 + u][dr]);
        *(u16x8*)dst = o0;
        *(u16x8*)(dst + 8) = o1;
    }
}

// ==================== MFMA flash attention v6 ================================
// R10: 256 q-rows/block (512 threads, 8 waves x 32 rows), grid 256 = perfect
// 1-generation packing. K/V staged ONCE per 256 q-rows (was twice per 128):
// per-CU staging LDS ops halve, K/V HBM fetch halves. Same 2-barrier tile
// structure as R8 (verified): {sync; stage K+V; refill regs; sync; QK^T ->
// exp -> P(wave-private) -> PV}. Q-rope in-register (R9, verified).
// LDS: Ks[64][136] 17KB + Vs[128][72] 18KB + Ps[256][72] 36KB = 71KB;
// epilogue scratch [256][136] = 68KB overlays after final sync.
// XCD locality: bi%8 == bh%8 (32 = 0 mod 8) -> all qt-blocks of a head on
// one XCD, K/V L2-resident.
__global__ __launch_bounds__(512, 1)
void k_flash_mfma(const ushort_t* __restrict__ Qb, const ushort_t* __restrict__ Kb,
                  const ushort_t* __restrict__ Vt,
                  const float* __restrict__ ct, const float* __restrict__ st,
                  ushort_t* __restrict__ ch, ushort_t* __restrict__ cl) {
    __shared__ ushort_t SH[36352];      // Ks @0 (8704) | Vs @8704 (9216) | Ps @17920 (18432)
    ushort_t* Ks = SH;
    ushort_t* Vs = SH + 8704;
    ushort_t* Ps = SH + 17920;
    const int tid = threadIdx.x;        // 0..511
    const int lane = tid & 63;
    const int w = tid >> 6;             // 0..7
    const int quad = lane >> 4;
    const int l15 = lane & 15;
    const int bi = blockIdx.x;          // 0..255
    const int bh = bi & 31;             // XCD swizzle: bh%8 == XCD id
    const int qt = bi >> 5;             // 0..7 (256 q rows each)
    const ushort_t* Qg = Qb + ((size_t)bh * SEQ + ((size_t)qt << 8)) * HD;
    const ushort_t* Kg = Kb + (size_t)bh * SEQ * HD;
    const ushort_t* Vg = Vt + (size_t)bh * HD * SEQ;

    // persistent Q fragments (B-operand), roped in-register (R9, verified).
    // Row sg = qt*256 + w*32 + qi*16 + l15; d = ks*32 + quad*8 + j.
    const float scq = 0.08838834764831845f;
    bf16x8 qf[2][4];
#pragma unroll
    for (int qi = 0; qi < 2; qi++) {
        const int row = w * 32 + qi * 16 + l15;
        const int sg = (qt << 8) + row;
        const int tb = (sg << 6) + quad * 8;
        float c0[8], s0[8], c1[8], s1[8];
        *(float4*)&c0[0] = *(const float4*)&ct[tb];
        *(float4*)&c0[4] = *(const float4*)&ct[tb + 4];
        *(float4*)&s0[0] = *(const float4*)&st[tb];
        *(float4*)&s0[4] = *(const float4*)&st[tb + 4];
        *(float4*)&c1[0] = *(const float4*)&ct[tb + 32];
        *(float4*)&c1[4] = *(const float4*)&ct[tb + 36];
        *(float4*)&s1[0] = *(const float4*)&st[tb + 32];
        *(float4*)&s1[4] = *(const float4*)&st[tb + 36];
        const ushort_t* qrow = Qg + (size_t)row * HD + quad * 8;
        u16x8 r0 = *(const u16x8*)(qrow);
        u16x8 r1 = *(const u16x8*)(qrow + 32);
        u16x8 r2 = *(const u16x8*)(qrow + 64);
        u16x8 r3 = *(const u16x8*)(qrow + 96);
        u16x8 f0, f1, f2, f3;
#pragma unroll
        for (int j = 0; j < 8; j++) {
            float a0 = bf2f(r0[j]), a1 = bf2f(r1[j]);
            float a2 = bf2f(r2[j]), a3 = bf2f(r3[j]);
            f0[j] = bf16r((a0 * c0[j] - a2 * s0[j]) * scq);
            f2[j] = bf16r((a2 * c0[j] + a0 * s0[j]) * scq);
            f1[j] = bf16r((a1 * c1[j] - a3 * s1[j]) * scq);
            f3[j] = bf16r((a3 * c1[j] + a1 * s1[j]) * scq);
        }
        qf[qi][0] = __builtin_bit_cast(bf16x8, f0);
        qf[qi][1] = __builtin_bit_cast(bf16x8, f1);
        qf[qi][2] = __builtin_bit_cast(bf16x8, f2);
        qf[qi][3] = __builtin_bit_cast(bf16x8, f3);
    }

    const int sr = tid >> 4;            // K staging row 0..31 (2 iters x 32)
    const int sc8 = (tid & 15) << 3;    // K staging col (16B)
    const int vr = tid >> 3;            // V staging row 0..63 (2 iters x 64)
    const int vc8 = (tid & 7) << 3;     // V staging col (16B)

    // prefetch tile 0: K rows [0,64), V^T cols [0,64)
    u16x8 Kreg[2], Vreg[2];
#pragma unroll
    for (int i = 0; i < 2; i++)
        Kreg[i] = *(const u16x8*)(Kg + (size_t)(i * 32 + sr) * HD + sc8);
#pragma unroll
    for (int i = 0; i < 2; i++)
        Vreg[i] = *(const u16x8*)(Vg + (size_t)(i * 64 + vr) * SEQ + vc8);

    f32x4 acc[2][8];
#pragma unroll
    for (int qi = 0; qi < 2; qi++)
#pragma unroll
        for (int d = 0; d < 8; d++) acc[qi][d] = (f32x4){0.f, 0.f, 0.f, 0.f};
    float lp[2] = {0.f, 0.f};

    for (int kt = 0; kt < SEQ; kt += 64) {
        const int np = kt + 64;
        __syncthreads();                // prev tile's kf/vf/pf reads done
#pragma unroll
        for (int i = 0; i < 2; i++)     // stage K tile
            *(u16x8*)&Ks[(i * 32 + sr) * 136 + sc8] = Kreg[i];
#pragma unroll
        for (int i = 0; i < 2; i++)     // stage V tile
            *(u16x8*)&Vs[(i * 64 + vr) * 72 + vc8] = Vreg[i];
        if (np < SEQ) {
#pragma unroll
            for (int i = 0; i < 2; i++)
                Kreg[i] = *(const u16x8*)(Kg + (size_t)(np + i * 32 + sr) * HD + sc8);
#pragma unroll
            for (int i = 0; i < 2; i++)
                Vreg[i] = *(const u16x8*)(Vg + (size_t)(i * 64 + vr) * SEQ + np + vc8);
        }
        __syncthreads();                // staging visible block-wide

        // ---- QK^T: sc[qi][j] = K(16 rows) x Q(16 rows)^T ----
        f32x4 sc[2][4];
#pragma unroll
        for (int qi = 0; qi < 2; qi++)
#pragma unroll
            for (int j = 0; j < 4; j++) sc[qi][j] = (f32x4){0.f, 0.f, 0.f, 0.f};
#pragma unroll
        for (int ks = 0; ks < 4; ks++) {
            bf16x8 kf[4];
#pragma unroll
            for (int j = 0; j < 4; j++)
                kf[j] = *(const bf16x8*)&Ks[(j * 16 + l15) * 136 + ks * 32 + quad * 8];
#pragma unroll
            for (int qi = 0; qi < 2; qi++)
#pragma unroll
                for (int j = 0; j < 4; j++)
                    sc[qi][j] = __builtin_amdgcn_mfma_f32_16x16x32_bf16(
                        kf[j], qf[qi][ks], sc[qi][j], 0, 0, 0);
        }

        // ---- p = exp(score); accumulate l; write P (wave-private rows) ----
#pragma unroll
        for (int qi = 0; qi < 2; qi++) {
            const int prow = (w * 32 + qi * 16 + l15) * 72 + quad * 4;
#pragma unroll
            for (int j = 0; j < 4; j++) {
                float p0 = __expf(sc[qi][j][0]);
                float p1 = __expf(sc[qi][j][1]);
                float p2 = __expf(sc[qi][j][2]);
                float p3 = __expf(sc[qi][j][3]);
                lp[qi] += (p0 + p1) + (p2 + p3);
                __hip_bfloat162 lo2 = __float22bfloat162_rn({p0, p1});
                __hip_bfloat162 hi2 = __float22bfloat162_rn({p2, p3});
                uint2 pk = make_uint2(*(u32*)&lo2, *(u32*)&hi2);
                *(uint2*)&Ps[prow + j * 16] = pk;
            }
        }

        // ---- PV: acc[qi][db] += V^T(16 d-rows) x P^T ----
#pragma unroll
        for (int ks = 0; ks < 2; ks++) {
            bf16x8 pf[2];
#pragma unroll
            for (int qi = 0; qi < 2; qi++)
                pf[qi] = *(const bf16x8*)&Ps[(w * 32 + qi * 16 + l15) * 72 + ks * 32 + quad * 8];
#pragma unroll
            for (int db = 0; db < 8; db++) {
                bf16x8 vf = *(const bf16x8*)&Vs[(db * 16 + l15) * 72 + ks * 32 + quad * 8];
#pragma unroll
                for (int qi = 0; qi < 2; qi++)
                    acc[qi][db] = __builtin_amdgcn_mfma_f32_16x16x32_bf16(vf, pf[qi], acc[qi][db], 0, 0, 0);
            }
        }
    }

    // ---- epilogue: l-reduce, normalize, re-layout via SH, coalesced store ----
    float inv[2];
#pragma unroll
    for (int qi = 0; qi < 2; qi++) {
        float l = lp[qi];
        l += __shfl_xor(l, 16);
        l += __shfl_xor(l, 32);
        inv[qi] = 1.0f / l;
    }
    const size_t obase = ((size_t)bh * SEQ + ((size_t)qt << 8)) * HD;

    __syncthreads();                    // final PV reads of Vs/Ps done
    // hi pass (SH reused as [256][136] scratch = 34816 ushorts <= 36352)
#pragma unroll
    for (int qi = 0; qi < 2; qi++)
#pragma unroll
        for (int db = 0; db < 8; db++) {
            ushort4 hh;
            ushort_t dum;
            split1(acc[qi][db][0] * inv[qi], hh.x, dum);
            split1(acc[qi][db][1] * inv[qi], hh.y, dum);
            split1(acc[qi][db][2] * inv[qi], hh.z, dum);
            split1(acc[qi][db][3] * inv[qi], hh.w, dum);
            *(ushort4*)&SH[(w * 32 + qi * 16 + l15) * 136 + db * 16 + quad * 4] = hh;
        }
    __syncthreads();
#pragma unroll
    for (int t2 = 0; t2 < 8; t2++) {
        int c = t2 * 512 + tid;
        int row = c >> 4, col8 = (c & 15) << 3;
        *(u16x8*)&ch[obase + (size_t)row * HD + col8] = *(const u16x8*)&SH[row * 136 + col8];
    }
    __syncthreads();
    // lo pass
#pragma unroll
    for (int qi = 0; qi < 2; qi++)
#pragma unroll
        for (int db = 0; db < 8; db++) {
            ushort4 ll;
            ushort_t dum;
            split1(acc[qi][db][0] * inv[qi], dum, ll.x);
            split1(acc[qi][db][1] * inv[qi], dum, ll.y);
            split1(acc[qi][db][2] * inv[qi], dum, ll.z);
            split1(acc[qi][db][3] * inv[qi], dum, ll.w);
            *(ushort4*)&SH[(w * 32 + qi * 16 + l15) * 136 + db * 16 + quad * 4] = ll;
        }
    __syncthreads();
#pragma unroll
    for (int t2 = 0; t2 < 8; t2++) {
        int c = t2 * 512 + tid;
        int row = c >> 4, col8 = (c & 15) << 3;
        *(u16x8*)&cl[obase + (size_t)row * HD + col8] = *(const u16x8*)&SH[row * 136 + col8];
    }
}

// ==================== launch =================================================
extern "C" void kernel_launch(void* const* d_in, const int* in_sizes, int n_in,
                              void* d_out, int out_size, void* d_ws, size_t ws_size,
                              hipStream_t stream) {
    const float* X  = (const float*)d_in[0];
    const float* Wq = (const float*)d_in[1];
    const float* bq = (const float*)d_in[2];
    const float* Wk = (const float*)d_in[3];
    const float* bk = (const float*)d_in[4];
    const float* Wv = (const float*)d_in[5];
    const float* bv = (const float*)d_in[6];
    const float* Wo = (const float*)d_in[7];
    const float* bo = (const float*)d_in[8];
    float* out = (float*)d_out;

    const size_t QS = (size_t)NB * NH * SEQ * HD;   // 8,388,608 elems
    const size_t WS = (size_t)HIDDEN * HIDDEN;      // 4,194,304 elems
    ushort_t* qb_ws = (ushort_t*)d_ws;              // bf16 blocked QKV outputs
    ushort_t* kb_ws = qb_ws + QS;
    ushort_t* vb_ws = kb_ws + QS;
    float* cost = (float*)(vb_ws + QS);
    float* sint = cost + (size_t)SEQ * 64;
    ushort_t* Xh = (ushort_t*)(sint + (size_t)SEQ * 64);
    ushort_t* Wh0 = Xh + QS;
    ushort_t* Wh1 = Wh0 + WS;
    ushort_t* Wh2 = Wh1 + WS;
    ushort_t* Woh = Wh2 + WS;
    ushort_t* Wol = Woh + WS;
    ushort_t* Kb  = Wol + WS;
    ushort_t* Vtb = Kb + QS;
    ushort_t* ctxh = Xh;                            // Xh dead after qkv8
    ushort_t* ctxl = kb_ws;                         // kb_ws dead after ropek

    k_cvt_all<<<TBLK + (XG + 4 * WG) / 256, 256, 0, stream>>>(
        (const float4*)X, (const float4*)Wq, (const float4*)Wk, (const float4*)Wv,
        (const float4*)Wo,
        (ushort4*)Xh, (ushort4*)Wh0, (ushort4*)Wh1, (ushort4*)Wh2,
        (ushort4*)Woh, (ushort4*)Wol, cost, sint);

    k_gemm_qkv8<<<384, 512, 0, stream>>>(Xh, Wh0, Wh1, Wh2, bq, bk, bv,
                                         qb_ws, kb_ws, vb_ws);

    k_ropek_vpack<<<4096, 256, 0, stream>>>(kb_ws, vb_ws, cost, sint, Kb, Vtb);

    k_flash_mfma<<<256, 512, 0, stream>>>(qb_ws, Kb, Vtb, cost, sint, ctxh, ctxl);

    k_gemm_o2<<<dim3(256), 512, 0, stream>>>(ctxh, ctxl, Woh, Wol, bo, out);
}